// Round 1
// baseline (936.952 us; speedup 1.0000x reference)
//
#include <hip/hip_runtime.h>
#include <math.h>

// EpisodicMemory baseline: all-fp32, correctness-first.
//   B=16384, D=512, E=1024, top_k=4 (hardcoded, matches setup_inputs).
// ws layout (98 MB):
//   [0,2MB)    keys_norm [E][D]
//   [2,34MB)   q / q_norm [B][D]   (overlaid by `retrieved` after sim GEMM)
//   [34,98MB)  sim [B][E]          (overlaid by `proj` after topk)

#define B_ 16384
#define D_ 512
#define E_ 1024

#define BM 128
#define BN 128
#define BK 8

// ---------- L2 normalize rows, one wave (64 lanes) per 512-float row ----------
__global__ __launch_bounds__(64) void l2norm_rows(const float* in, float* out) {
  const int row  = blockIdx.x;
  const int lane = threadIdx.x;
  const float4* p4 = (const float4*)(in + (size_t)row * D_);
  float4 a = p4[lane];
  float4 b = p4[lane + 64];
  float ss = a.x*a.x + a.y*a.y + a.z*a.z + a.w*a.w
           + b.x*b.x + b.y*b.y + b.z*b.z + b.w*b.w;
#pragma unroll
  for (int off = 32; off > 0; off >>= 1) ss += __shfl_xor(ss, off, 64);
  const float inv = 1.0f / fmaxf(sqrtf(ss), 1e-12f);
  a.x *= inv; a.y *= inv; a.z *= inv; a.w *= inv;
  b.x *= inv; b.y *= inv; b.z *= inv; b.w *= inv;
  float4* o4 = (float4*)(out + (size_t)row * D_);
  o4[lane]      = a;
  o4[lane + 64] = b;
}

// ---------- generic NT SGEMM: C[M,N] = A[M,K] * B[N,K]^T (all row-major) ------
// 256 threads, 128x128 block tile, 8x8 per-thread tile, k-major LDS.
__global__ __launch_bounds__(256) void sgemm_nt(const float* __restrict__ A,
                                                const float* __restrict__ Bm,
                                                float* __restrict__ C,
                                                int M, int N, int K) {
  __shared__ float As[BK][BM];
  __shared__ float Bs[BK][BN];
  const int tid = threadIdx.x;
  const int bn = blockIdx.x, bm = blockIdx.y;
  const int tm = tid >> 4, tn = tid & 15;          // 16x16 thread grid
  const int lrow = tid >> 1, lk4 = (tid & 1) * 4;  // staging: 2 threads/row
  const float* Ap = A  + (size_t)(bm * BM + lrow) * K + lk4;
  const float* Bp = Bm + (size_t)(bn * BN + lrow) * K + lk4;

  float acc[8][8];
#pragma unroll
  for (int i = 0; i < 8; i++)
#pragma unroll
    for (int j = 0; j < 8; j++) acc[i][j] = 0.0f;

  for (int k0 = 0; k0 < K; k0 += BK) {
    const float4 av = *(const float4*)(Ap + k0);
    const float4 bv = *(const float4*)(Bp + k0);
    As[lk4 + 0][lrow] = av.x; As[lk4 + 1][lrow] = av.y;
    As[lk4 + 2][lrow] = av.z; As[lk4 + 3][lrow] = av.w;
    Bs[lk4 + 0][lrow] = bv.x; Bs[lk4 + 1][lrow] = bv.y;
    Bs[lk4 + 2][lrow] = bv.z; Bs[lk4 + 3][lrow] = bv.w;
    __syncthreads();
#pragma unroll
    for (int k = 0; k < BK; k++) {
      float a[8], b[8];
#pragma unroll
      for (int i = 0; i < 8; i++) a[i] = As[k][tm + 16 * i];
#pragma unroll
      for (int j = 0; j < 8; j++) b[j] = Bs[k][tn + 16 * j];
#pragma unroll
      for (int i = 0; i < 8; i++)
#pragma unroll
        for (int j = 0; j < 8; j++) acc[i][j] = fmaf(a[i], b[j], acc[i][j]);
    }
    __syncthreads();
  }

#pragma unroll
  for (int i = 0; i < 8; i++) {
    const int row = bm * BM + tm + 16 * i;
    float* Cp = C + (size_t)row * N + bn * BN + tn;
#pragma unroll
    for (int j = 0; j < 8; j++) Cp[16 * j] = acc[i][j];
  }
}

// ---------- gate GEMM: out = sigmoid([query,proj] @ Wg^T + bg) * proj ---------
__global__ __launch_bounds__(256) void gate_gemm(const float* __restrict__ query,
                                                 const float* __restrict__ proj,
                                                 const float* __restrict__ Wg,
                                                 const float* __restrict__ bg,
                                                 float* __restrict__ out) {
  __shared__ float As[BK][BM];
  __shared__ float Bs[BK][BN];
  const int tid = threadIdx.x;
  const int bn = blockIdx.x, bm = blockIdx.y;
  const int tm = tid >> 4, tn = tid & 15;
  const int lrow = tid >> 1, lk4 = (tid & 1) * 4;
  const size_t arow = (size_t)(bm * BM + lrow);
  const float* Bp = Wg + (size_t)(bn * BN + lrow) * (2 * D_) + lk4;

  float acc[8][8];
#pragma unroll
  for (int i = 0; i < 8; i++)
#pragma unroll
    for (int j = 0; j < 8; j++) acc[i][j] = 0.0f;

  for (int k0 = 0; k0 < 2 * D_; k0 += BK) {
    const float* Asrc = (k0 < D_) ? (query + arow * D_ + k0 + lk4)
                                  : (proj + arow * D_ + (k0 - D_) + lk4);
    const float4 av = *(const float4*)Asrc;
    const float4 bv = *(const float4*)(Bp + k0);
    As[lk4 + 0][lrow] = av.x; As[lk4 + 1][lrow] = av.y;
    As[lk4 + 2][lrow] = av.z; As[lk4 + 3][lrow] = av.w;
    Bs[lk4 + 0][lrow] = bv.x; Bs[lk4 + 1][lrow] = bv.y;
    Bs[lk4 + 2][lrow] = bv.z; Bs[lk4 + 3][lrow] = bv.w;
    __syncthreads();
#pragma unroll
    for (int k = 0; k < BK; k++) {
      float a[8], b[8];
#pragma unroll
      for (int i = 0; i < 8; i++) a[i] = As[k][tm + 16 * i];
#pragma unroll
      for (int j = 0; j < 8; j++) b[j] = Bs[k][tn + 16 * j];
#pragma unroll
      for (int i = 0; i < 8; i++)
#pragma unroll
        for (int j = 0; j < 8; j++) acc[i][j] = fmaf(a[i], b[j], acc[i][j]);
    }
    __syncthreads();
  }

#pragma unroll
  for (int i = 0; i < 8; i++) {
    const int row = bm * BM + tm + 16 * i;
#pragma unroll
    for (int j = 0; j < 8; j++) {
      const int col = bn * BN + tn + 16 * j;
      const float x = acc[i][j] + bg[col];
      const float g = 1.0f / (1.0f + expf(-x));
      out[(size_t)row * D_ + col] = g * proj[(size_t)row * D_ + col];
    }
  }
}

// ---------- top-4 + softmax + weighted gather of values ----------------------
__global__ __launch_bounds__(256) void topk_retrieve(const float* __restrict__ sim,
                                                     const float* __restrict__ values,
                                                     float* __restrict__ retrieved) {
  const int b   = blockIdx.x;
  const int tid = threadIdx.x;
  __shared__ float sv[E_];
  __shared__ float rv[256];
  __shared__ int   ri[256];
  __shared__ float s_topv[4];
  __shared__ int   s_topi[4];

  const float* srow = sim + (size_t)b * E_;
#pragma unroll
  for (int m = 0; m < 4; m++) sv[tid + 256 * m] = srow[tid + 256 * m];
  __syncthreads();

  for (int k = 0; k < 4; k++) {
    float bv = -3.402823466e38f;
    int   bi = 0x7fffffff;
#pragma unroll
    for (int m = 0; m < 4; m++) {
      const int i = tid + 256 * m;
      const float v = sv[i];
      if (v > bv || (v == bv && i < bi)) { bv = v; bi = i; }
    }
    rv[tid] = bv; ri[tid] = bi;
    __syncthreads();
    for (int s = 128; s > 0; s >>= 1) {
      if (tid < s) {
        const float v2 = rv[tid + s];
        const int   i2 = ri[tid + s];
        if (v2 > rv[tid] || (v2 == rv[tid] && i2 < ri[tid])) { rv[tid] = v2; ri[tid] = i2; }
      }
      __syncthreads();
    }
    if (tid == 0) {
      s_topv[k] = rv[0];
      s_topi[k] = ri[0];
      sv[ri[0]] = -3.402823466e38f;  // exclude from next pass
    }
    __syncthreads();
  }

  // softmax over 5*topv (max is s_topv[0] -- selected in descending order)
  const float mx = 5.0f * s_topv[0];
  float w[4], wsum = 0.0f;
#pragma unroll
  for (int k = 0; k < 4; k++) { w[k] = expf(5.0f * s_topv[k] - mx); wsum += w[k]; }
  const float winv = 1.0f / wsum;
#pragma unroll
  for (int k = 0; k < 4; k++) w[k] *= winv;

  const int i0 = s_topi[0], i1 = s_topi[1], i2 = s_topi[2], i3 = s_topi[3];
  for (int c = tid; c < D_; c += 256) {
    float r = w[0] * values[(size_t)i0 * D_ + c]
            + w[1] * values[(size_t)i1 * D_ + c]
            + w[2] * values[(size_t)i2 * D_ + c]
            + w[3] * values[(size_t)i3 * D_ + c];
    retrieved[(size_t)b * D_ + c] = r;
  }
}

extern "C" void kernel_launch(void* const* d_in, const int* in_sizes, int n_in,
                              void* d_out, int out_size, void* d_ws, size_t ws_size,
                              hipStream_t stream) {
  (void)in_sizes; (void)n_in; (void)out_size; (void)ws_size;
  const float* query = (const float*)d_in[0];
  const float* keys  = (const float*)d_in[1];
  const float* vals  = (const float*)d_in[2];
  const float* Wq    = (const float*)d_in[3];
  const float* Wv    = (const float*)d_in[4];
  const float* Wg    = (const float*)d_in[5];
  const float* bg    = (const float*)d_in[6];
  float* out = (float*)d_out;

  char* ws = (char*)d_ws;
  float* keys_norm = (float*)(ws);                        // 2 MB
  float* q         = (float*)(ws + (size_t)(2  << 20));   // 32 MB
  float* sim       = (float*)(ws + (size_t)(34 << 20));   // 64 MB
  float* retrieved = q;    // q dead after sim GEMM
  float* proj      = sim;  // sim dead after topk

  l2norm_rows<<<E_, 64, 0, stream>>>(keys, keys_norm);
  sgemm_nt<<<dim3(D_ / BN, B_ / BM), 256, 0, stream>>>(query, Wq, q, B_, D_, D_);
  l2norm_rows<<<B_, 64, 0, stream>>>(q, q);
  sgemm_nt<<<dim3(E_ / BN, B_ / BM), 256, 0, stream>>>(q, keys_norm, sim, B_, E_, D_);
  topk_retrieve<<<B_, 256, 0, stream>>>(sim, vals, retrieved);
  sgemm_nt<<<dim3(D_ / BN, B_ / BM), 256, 0, stream>>>(retrieved, Wv, proj, B_, D_, D_);
  gate_gemm<<<dim3(D_ / BN, B_ / BM), 256, 0, stream>>>(query, proj, Wg, bg, out);
}

// Round 2
// 554.214 us; speedup vs baseline: 1.6906x; 1.6906x over previous
//
#include <hip/hip_runtime.h>
#include <hip/hip_bf16.h>
#include <math.h>

// EpisodicMemory round 2: bf16 MFMA for Wv + gate GEMMs; fp32 ranking path.
// B=16384, D=512, E=1024, top_k=4.
// ws layout (<= 98 MB):
//   [0,2M)    keys_norm fp32  -> after sim GEMM: topw(256K)+topi(256K)
//   [2M,34M)  q fp32          -> after sim GEMM: proj_f32
//   [34M,98M) sim fp32        -> after topk_select: retr_bf[34M), proj_bf[50M),
//                                query_bf[66M), Wv_bf[82M), Wg_bf[82M+512K)

#define B_ 16384
#define D_ 512
#define E_ 1024

typedef __attribute__((ext_vector_type(8))) short bf16x8;
typedef __attribute__((ext_vector_type(4))) float f32x4;
typedef __attribute__((ext_vector_type(8))) unsigned short u16x8;

__device__ __forceinline__ unsigned short f2bf(float f) {
  unsigned u = __builtin_bit_cast(unsigned, f);
  unsigned r = (u + 0x7fffu + ((u >> 16) & 1u)) >> 16;
  return (unsigned short)r;
}

#define GLDS16(g, l)                                                          \
  __builtin_amdgcn_global_load_lds(                                           \
      (const __attribute__((address_space(1))) void*)(g),                     \
      (__attribute__((address_space(3))) void*)(l), 16, 0, 0)

// ---------- L2 normalize rows, one wave per 512-float row --------------------
__global__ __launch_bounds__(64) void l2norm_rows(const float* in, float* out) {
  const int row  = blockIdx.x;
  const int lane = threadIdx.x;
  const float4* p4 = (const float4*)(in + (size_t)row * D_);
  float4 a = p4[lane];
  float4 b = p4[lane + 64];
  float ss = a.x*a.x + a.y*a.y + a.z*a.z + a.w*a.w
           + b.x*b.x + b.y*b.y + b.z*b.z + b.w*b.w;
#pragma unroll
  for (int off = 32; off > 0; off >>= 1) ss += __shfl_xor(ss, off, 64);
  const float inv = 1.0f / fmaxf(sqrtf(ss), 1e-12f);
  a.x *= inv; a.y *= inv; a.z *= inv; a.w *= inv;
  b.x *= inv; b.y *= inv; b.z *= inv; b.w *= inv;
  float4* o4 = (float4*)(out + (size_t)row * D_);
  o4[lane]      = a;
  o4[lane + 64] = b;
}

// ---------- fp32 NT SGEMM (ranking path): C[M,N] = A[M,K]*B[N,K]^T -----------
#define BM 128
#define BN 128
#define BKf 8
__global__ __launch_bounds__(256) void sgemm_nt(const float* __restrict__ A,
                                                const float* __restrict__ Bm,
                                                float* __restrict__ C,
                                                int M, int N, int K) {
  __shared__ float As[BKf][BM];
  __shared__ float Bs[BKf][BN];
  const int tid = threadIdx.x;
  const int bn = blockIdx.x, bm = blockIdx.y;
  const int tm = tid >> 4, tn = tid & 15;
  const int lrow = tid >> 1, lk4 = (tid & 1) * 4;
  const float* Ap = A  + (size_t)(bm * BM + lrow) * K + lk4;
  const float* Bp = Bm + (size_t)(bn * BN + lrow) * K + lk4;

  float acc[8][8];
#pragma unroll
  for (int i = 0; i < 8; i++)
#pragma unroll
    for (int j = 0; j < 8; j++) acc[i][j] = 0.0f;

  for (int k0 = 0; k0 < K; k0 += BKf) {
    const float4 av = *(const float4*)(Ap + k0);
    const float4 bv = *(const float4*)(Bp + k0);
    As[lk4 + 0][lrow] = av.x; As[lk4 + 1][lrow] = av.y;
    As[lk4 + 2][lrow] = av.z; As[lk4 + 3][lrow] = av.w;
    Bs[lk4 + 0][lrow] = bv.x; Bs[lk4 + 1][lrow] = bv.y;
    Bs[lk4 + 2][lrow] = bv.z; Bs[lk4 + 3][lrow] = bv.w;
    __syncthreads();
#pragma unroll
    for (int k = 0; k < BKf; k++) {
      float a[8], b[8];
#pragma unroll
      for (int i = 0; i < 8; i++) a[i] = As[k][tm + 16 * i];
#pragma unroll
      for (int j = 0; j < 8; j++) b[j] = Bs[k][tn + 16 * j];
#pragma unroll
      for (int i = 0; i < 8; i++)
#pragma unroll
        for (int j = 0; j < 8; j++) acc[i][j] = fmaf(a[i], b[j], acc[i][j]);
    }
    __syncthreads();
  }
#pragma unroll
  for (int i = 0; i < 8; i++) {
    const int row = bm * BM + tm + 16 * i;
    float* Cp = C + (size_t)row * N + bn * BN + tn;
#pragma unroll
    for (int j = 0; j < 8; j++) Cp[16 * j] = acc[i][j];
  }
}

// ---------- top-4 select + softmax weights (no gather) -----------------------
__global__ __launch_bounds__(256) void topk_select(const float* __restrict__ sim,
                                                   float4* __restrict__ topw,
                                                   int4* __restrict__ topi) {
  const int b   = blockIdx.x;
  const int tid = threadIdx.x;
  __shared__ float sv[E_];
  __shared__ float rv[256];
  __shared__ int   ri[256];
  __shared__ float s_topv[4];
  __shared__ int   s_topi[4];

  const float* srow = sim + (size_t)b * E_;
#pragma unroll
  for (int m = 0; m < 4; m++) sv[tid + 256 * m] = srow[tid + 256 * m];
  __syncthreads();

  for (int k = 0; k < 4; k++) {
    float bv = -3.402823466e38f;
    int   bi = 0x7fffffff;
#pragma unroll
    for (int m = 0; m < 4; m++) {
      const int i = tid + 256 * m;
      const float v = sv[i];
      if (v > bv || (v == bv && i < bi)) { bv = v; bi = i; }
    }
    rv[tid] = bv; ri[tid] = bi;
    __syncthreads();
    for (int s = 128; s > 0; s >>= 1) {
      if (tid < s) {
        const float v2 = rv[tid + s];
        const int   i2 = ri[tid + s];
        if (v2 > rv[tid] || (v2 == rv[tid] && i2 < ri[tid])) { rv[tid] = v2; ri[tid] = i2; }
      }
      __syncthreads();
    }
    if (tid == 0) {
      s_topv[k] = rv[0];
      s_topi[k] = ri[0];
      sv[ri[0]] = -3.402823466e38f;
    }
    __syncthreads();
  }

  if (tid == 0) {
    const float mx = 5.0f * s_topv[0];
    float w[4], wsum = 0.0f;
#pragma unroll
    for (int k = 0; k < 4; k++) { w[k] = expf(5.0f * s_topv[k] - mx); wsum += w[k]; }
    const float winv = 1.0f / wsum;
    topw[b] = make_float4(w[0]*winv, w[1]*winv, w[2]*winv, w[3]*winv);
    topi[b] = make_int4(s_topi[0], s_topi[1], s_topi[2], s_topi[3]);
  }
}

// ---------- gather: retrieved(bf16) = sum_k w[k] * values[idx[k]] ------------
__global__ __launch_bounds__(128) void retrieve_gather(const float4* __restrict__ topw,
                                                       const int4* __restrict__ topi,
                                                       const float* __restrict__ values,
                                                       unsigned short* __restrict__ retr_bf) {
  const int b = blockIdx.x;
  const int t = threadIdx.x;           // 128 threads x 4 cols
  const float4 w = topw[b];
  const int4   ii = topi[b];
  const float4 v0 = *(const float4*)(values + (size_t)ii.x * D_ + 4*t);
  const float4 v1 = *(const float4*)(values + (size_t)ii.y * D_ + 4*t);
  const float4 v2 = *(const float4*)(values + (size_t)ii.z * D_ + 4*t);
  const float4 v3 = *(const float4*)(values + (size_t)ii.w * D_ + 4*t);
  const float r0 = w.x*v0.x + w.y*v1.x + w.z*v2.x + w.w*v3.x;
  const float r1 = w.x*v0.y + w.y*v1.y + w.z*v2.y + w.w*v3.y;
  const float r2 = w.x*v0.z + w.y*v1.z + w.z*v2.z + w.w*v3.z;
  const float r3 = w.x*v0.w + w.y*v1.w + w.z*v2.w + w.w*v3.w;
  ushort4 o;
  o.x = f2bf(r0); o.y = f2bf(r1); o.z = f2bf(r2); o.w = f2bf(r3);
  *(ushort4*)(retr_bf + (size_t)b * D_ + 4*t) = o;
}

// ---------- fp32 -> bf16 conversion ------------------------------------------
__global__ __launch_bounds__(256) void cvt_bf16(const float* __restrict__ in,
                                                unsigned short* __restrict__ out, int n8) {
  const int i = blockIdx.x * 256 + threadIdx.x;
  if (i >= n8) return;
  const float4 a = ((const float4*)in)[2*i];
  const float4 b = ((const float4*)in)[2*i+1];
  u16x8 o;
  o[0]=f2bf(a.x); o[1]=f2bf(a.y); o[2]=f2bf(a.z); o[3]=f2bf(a.w);
  o[4]=f2bf(b.x); o[5]=f2bf(b.y); o[6]=f2bf(b.z); o[7]=f2bf(b.w);
  *(u16x8*)(out + 8*i) = o;
}

// ---------- bf16 MFMA NT GEMM, 128x128 tile, BK=32, double-buffered ----------
// C[M,512] = A[M,KTOT] * Bw[512,KTOT]^T.  GATE: A = concat(A0,A1) halves
// (each [M,512]); epilogue = sigmoid(acc+bg)*projf -> outf.
// !GATE: A = A0 [M,512]; epilogue: outf=acc (fp32), outbf=bf16(acc).
// LDS swizzle: chunk c of row r holds global k-chunk (c ^ ((r>>1)&3)).
template<int KTOT, bool GATE>
__global__ __launch_bounds__(256) void mfma_nt(
    const unsigned short* __restrict__ A0,
    const unsigned short* __restrict__ A1,
    const unsigned short* __restrict__ Bw,
    const float* __restrict__ bg,
    const float* __restrict__ projf,
    float* __restrict__ outf,
    unsigned short* __restrict__ outbf) {
  __shared__ __align__(16) unsigned short As[2][128 * 32];
  __shared__ __align__(16) unsigned short Bs[2][128 * 32];
  const int tid = threadIdx.x;
  const int wv = tid >> 6, l = tid & 63;
  const int bn = blockIdx.x, bm = blockIdx.y;
  const int wr = wv >> 1, wc = wv & 1;
  const int lane16 = l & 15, lhi = l >> 4;

  f32x4 acc[4][4];
#pragma unroll
  for (int mi = 0; mi < 4; mi++)
#pragma unroll
    for (int nj = 0; nj < 4; nj++)
#pragma unroll
      for (int r = 0; r < 4; r++) acc[mi][nj][r] = 0.0f;

  auto stage = [&](int buf, int t) {
    const int k0 = t * 32;
#pragma unroll
    for (int h = 0; h < 2; ++h) {
      const int p = tid + 256 * h;          // chunk index 0..511
      const int r = p >> 2, c = p & 3;
      const int q = k0 + 8 * (c ^ ((r >> 1) & 3));
      const unsigned short* asrc;
      if constexpr (GATE) {
        asrc = (q < 512 ? A0 : A1) + (size_t)(bm * 128 + r) * 512 + (q & 511);
      } else {
        asrc = A0 + (size_t)(bm * 128 + r) * 512 + q;
      }
      GLDS16(asrc, &As[buf][(4 * h + wv) * 512]);
      const unsigned short* bsrc = Bw + (size_t)(bn * 128 + r) * KTOT + q;
      GLDS16(bsrc, &Bs[buf][(4 * h + wv) * 512]);
    }
  };

  auto compute = [&](int buf) {
    const int achunk = lhi ^ ((lane16 >> 1) & 3);
    bf16x8 af[4], bfr[4];
#pragma unroll
    for (int mi = 0; mi < 4; ++mi)
      af[mi] = *(const bf16x8*)&As[buf][(wr * 64 + mi * 16 + lane16) * 32 + achunk * 8];
#pragma unroll
    for (int nj = 0; nj < 4; ++nj)
      bfr[nj] = *(const bf16x8*)&Bs[buf][(wc * 64 + nj * 16 + lane16) * 32 + achunk * 8];
#pragma unroll
    for (int mi = 0; mi < 4; ++mi)
#pragma unroll
      for (int nj = 0; nj < 4; ++nj)
        acc[mi][nj] = __builtin_amdgcn_mfma_f32_16x16x32_bf16(af[mi], bfr[nj], acc[mi][nj], 0, 0, 0);
  };

  const int NT = KTOT / 32;
  stage(0, 0);
  __syncthreads();
  for (int t = 0; t < NT - 1; ++t) {
    stage((t + 1) & 1, t + 1);
    compute(t & 1);
    __syncthreads();
  }
  compute((NT - 1) & 1);

  const int rowb = bm * 128 + wr * 64 + (lhi << 2);
  const int colb = bn * 128 + wc * 64 + lane16;
#pragma unroll
  for (int mi = 0; mi < 4; ++mi) {
#pragma unroll
    for (int nj = 0; nj < 4; ++nj) {
      const int col = colb + nj * 16;
#pragma unroll
      for (int r = 0; r < 4; ++r) {
        const int row = rowb + mi * 16 + r;
        const size_t o = (size_t)row * 512 + col;
        const float v = acc[mi][nj][r];
        if constexpr (GATE) {
          const float x = v + bg[col];
          const float g = 1.0f / (1.0f + __expf(-x));
          outf[o] = g * projf[o];
        } else {
          outf[o]  = v;
          outbf[o] = f2bf(v);
        }
      }
    }
  }
}

extern "C" void kernel_launch(void* const* d_in, const int* in_sizes, int n_in,
                              void* d_out, int out_size, void* d_ws, size_t ws_size,
                              hipStream_t stream) {
  (void)in_sizes; (void)n_in; (void)out_size; (void)ws_size;
  const float* query = (const float*)d_in[0];
  const float* keys  = (const float*)d_in[1];
  const float* vals  = (const float*)d_in[2];
  const float* Wq    = (const float*)d_in[3];
  const float* Wv    = (const float*)d_in[4];
  const float* Wg    = (const float*)d_in[5];
  const float* bg    = (const float*)d_in[6];
  float* out = (float*)d_out;

  char* ws = (char*)d_ws;
  float* keys_norm = (float*)(ws);                               // [0,2M)
  float4* topw     = (float4*)(ws);                              // overlays keys_norm
  int4*   topi     = (int4*)(ws + (256u << 10));
  float* q         = (float*)(ws + (2u << 20));                  // [2M,34M)
  float* projf     = q;                                          // overlays q
  float* sim       = (float*)(ws + (34u << 20));                 // [34M,98M)
  unsigned short* retr_bf  = (unsigned short*)(ws + (34u << 20));
  unsigned short* proj_bf  = (unsigned short*)(ws + (50u << 20));
  unsigned short* query_bf = (unsigned short*)(ws + (66u << 20));
  unsigned short* Wv_bf    = (unsigned short*)(ws + (82u << 20));
  unsigned short* Wg_bf    = (unsigned short*)(ws + (82u << 20) + 512u * 1024u);

  // ---- fp32 ranking path (must match numpy fp32) ----
  l2norm_rows<<<E_, 64, 0, stream>>>(keys, keys_norm);
  sgemm_nt<<<dim3(D_ / BN, B_ / BM), 256, 0, stream>>>(query, Wq, q, B_, D_, D_);
  l2norm_rows<<<B_, 64, 0, stream>>>(q, q);
  sgemm_nt<<<dim3(E_ / BN, B_ / BM), 256, 0, stream>>>(q, keys_norm, sim, B_, E_, D_);
  topk_select<<<B_, 256, 0, stream>>>(sim, topw, topi);
  retrieve_gather<<<B_, 128, 0, stream>>>(topw, topi, vals, retr_bf);

  // ---- bf16 conversions (write into dead sim region; after topk_select) ----
  cvt_bf16<<<(B_ * D_ / 8 + 255) / 256, 256, 0, stream>>>(query, query_bf, B_ * D_ / 8);
  cvt_bf16<<<(D_ * D_ / 8 + 255) / 256, 256, 0, stream>>>(Wv, Wv_bf, D_ * D_ / 8);
  cvt_bf16<<<(D_ * 2 * D_ / 8 + 255) / 256, 256, 0, stream>>>(Wg, Wg_bf, D_ * 2 * D_ / 8);

  // ---- bf16 MFMA GEMMs ----
  mfma_nt<512, false><<<dim3(4, B_ / 128), 256, 0, stream>>>(
      retr_bf, nullptr, Wv_bf, nullptr, nullptr, projf, proj_bf);
  mfma_nt<1024, true><<<dim3(4, B_ / 128), 256, 0, stream>>>(
      query_bf, proj_bf, Wg_bf, bg, projf, out, nullptr);
}

// Round 3
// 514.581 us; speedup vs baseline: 1.8208x; 1.0770x over previous
//
#include <hip/hip_runtime.h>
#include <hip/hip_bf16.h>
#include <math.h>

// EpisodicMemory round 3.
// fp32 exact path: Wq GEMM (b128-LDS sgemm) -> q; rescore top-candidates.
// bf16 MFMA: coarse sim, Wv GEMM, gate GEMM.
// ws layout (85 MB used, 98 MB proven):
//   [0,32M)   q fp32 (Wq->topk)          -> projF (Wv->gate)
//   [32M,64M) sim_bf (sim->topk)         -> proj_bf@32M (Wv->gate)
//   [64M,80M) qn_bf (l2q->sim)           -> retr_bf (topk->Wv)
//   [80M,82M) keysN fp32   [82M,83M) kn_bf   [83M,83.5M) Wv_bf
//   [84M,85M) Wg_bf        [85M,+64K) invq

#define B_ 16384
#define D_ 512
#define E_ 1024
#define MAXC 28

typedef __attribute__((ext_vector_type(8))) short bf16x8;
typedef __attribute__((ext_vector_type(4))) float f32x4;
typedef __attribute__((ext_vector_type(8))) unsigned short u16x8;

__device__ __forceinline__ unsigned short f2bf(float f) {
  unsigned u = __builtin_bit_cast(unsigned, f);
  unsigned r = (u + 0x7fffu + ((u >> 16) & 1u)) >> 16;
  return (unsigned short)r;
}
__device__ __forceinline__ float bf2f(unsigned short u) {
  return __builtin_bit_cast(float, (unsigned)u << 16);
}

#define GLDS16(g, l)                                                          \
  __builtin_amdgcn_global_load_lds(                                           \
      (const __attribute__((address_space(1))) void*)(g),                     \
      (__attribute__((address_space(3))) void*)(l), 16, 0, 0)

// ---------- L2 normalize keys: fp32 out + bf16 out ---------------------------
__global__ __launch_bounds__(64) void l2norm_keys(const float* __restrict__ in,
                                                  float* __restrict__ outF,
                                                  unsigned short* __restrict__ outBF) {
  const int row  = blockIdx.x;
  const int lane = threadIdx.x;
  const float4* p4 = (const float4*)(in + (size_t)row * D_);
  float4 a = p4[lane];
  float4 b = p4[lane + 64];
  float ss = a.x*a.x + a.y*a.y + a.z*a.z + a.w*a.w
           + b.x*b.x + b.y*b.y + b.z*b.z + b.w*b.w;
#pragma unroll
  for (int off = 32; off > 0; off >>= 1) ss += __shfl_xor(ss, off, 64);
  const float inv = 1.0f / fmaxf(sqrtf(ss), 1e-12f);
  a.x *= inv; a.y *= inv; a.z *= inv; a.w *= inv;
  b.x *= inv; b.y *= inv; b.z *= inv; b.w *= inv;
  float4* o4 = (float4*)(outF + (size_t)row * D_);
  o4[lane]      = a;
  o4[lane + 64] = b;
  ushort4 ua, ub;
  ua.x=f2bf(a.x); ua.y=f2bf(a.y); ua.z=f2bf(a.z); ua.w=f2bf(a.w);
  ub.x=f2bf(b.x); ub.y=f2bf(b.y); ub.z=f2bf(b.z); ub.w=f2bf(b.w);
  *(ushort4*)(outBF + (size_t)row * D_ + 4*lane)       = ua;
  *(ushort4*)(outBF + (size_t)row * D_ + 256 + 4*lane) = ub;
}

// ---------- L2 normalize q: bf16 normalized out + inv-norm (q untouched) -----
__global__ __launch_bounds__(64) void l2norm_q(const float* __restrict__ in,
                                               unsigned short* __restrict__ outBF,
                                               float* __restrict__ invq) {
  const int row  = blockIdx.x;
  const int lane = threadIdx.x;
  const float4* p4 = (const float4*)(in + (size_t)row * D_);
  float4 a = p4[lane];
  float4 b = p4[lane + 64];
  float ss = a.x*a.x + a.y*a.y + a.z*a.z + a.w*a.w
           + b.x*b.x + b.y*b.y + b.z*b.z + b.w*b.w;
#pragma unroll
  for (int off = 32; off > 0; off >>= 1) ss += __shfl_xor(ss, off, 64);
  const float inv = 1.0f / fmaxf(sqrtf(ss), 1e-12f);
  ushort4 ua, ub;
  ua.x=f2bf(a.x*inv); ua.y=f2bf(a.y*inv); ua.z=f2bf(a.z*inv); ua.w=f2bf(a.w*inv);
  ub.x=f2bf(b.x*inv); ub.y=f2bf(b.y*inv); ub.z=f2bf(b.z*inv); ub.w=f2bf(b.w*inv);
  *(ushort4*)(outBF + (size_t)row * D_ + 4*lane)       = ua;
  *(ushort4*)(outBF + (size_t)row * D_ + 256 + 4*lane) = ub;
  if (lane == 0) invq[row] = inv;
}

// ---------- fp32 NT SGEMM, b128 LDS reads: C[M,N]=A[M,K]*B[N,K]^T ------------
#define BM 128
#define BN 128
#define BKf 8
__global__ __launch_bounds__(256) void sgemm_v2(const float* __restrict__ A,
                                                const float* __restrict__ Bm,
                                                float* __restrict__ C,
                                                int M, int N, int K) {
  __shared__ float As[BKf][BM];
  __shared__ float Bs[BKf][BN];
  const int tid = threadIdx.x;
  const int bn = blockIdx.x, bm = blockIdx.y;
  const int tm = (tid >> 4) & 15, tn = tid & 15;
  const int lrow = tid >> 1, lk4 = (tid & 1) * 4;
  const float* Ap = A  + (size_t)(bm * BM + lrow) * K + lk4;
  const float* Bp = Bm + (size_t)(bn * BN + lrow) * K + lk4;

  float acc[8][8];
#pragma unroll
  for (int i = 0; i < 8; i++)
#pragma unroll
    for (int j = 0; j < 8; j++) acc[i][j] = 0.0f;

  for (int k0 = 0; k0 < K; k0 += BKf) {
    const float4 av = *(const float4*)(Ap + k0);
    const float4 bv = *(const float4*)(Bp + k0);
    As[lk4 + 0][lrow] = av.x; As[lk4 + 1][lrow] = av.y;
    As[lk4 + 2][lrow] = av.z; As[lk4 + 3][lrow] = av.w;
    Bs[lk4 + 0][lrow] = bv.x; Bs[lk4 + 1][lrow] = bv.y;
    Bs[lk4 + 2][lrow] = bv.z; Bs[lk4 + 3][lrow] = bv.w;
    __syncthreads();
#pragma unroll
    for (int k = 0; k < BKf; k++) {
      const float4 alo = *(const float4*)&As[k][tm * 4];
      const float4 ahi = *(const float4*)&As[k][64 + tm * 4];
      const float4 blo = *(const float4*)&Bs[k][tn * 4];
      const float4 bhi = *(const float4*)&Bs[k][64 + tn * 4];
      const float a[8] = {alo.x, alo.y, alo.z, alo.w, ahi.x, ahi.y, ahi.z, ahi.w};
      const float b[8] = {blo.x, blo.y, blo.z, blo.w, bhi.x, bhi.y, bhi.z, bhi.w};
#pragma unroll
      for (int i = 0; i < 8; i++)
#pragma unroll
        for (int j = 0; j < 8; j++) acc[i][j] = fmaf(a[i], b[j], acc[i][j]);
    }
    __syncthreads();
  }
#pragma unroll
  for (int i = 0; i < 8; i++) {
    const int row = bm * BM + (i >> 2) * 64 + tm * 4 + (i & 3);
    float4 lo = make_float4(acc[i][0], acc[i][1], acc[i][2], acc[i][3]);
    float4 hi = make_float4(acc[i][4], acc[i][5], acc[i][6], acc[i][7]);
    *(float4*)(C + (size_t)row * N + bn * BN + tn * 4)      = lo;
    *(float4*)(C + (size_t)row * N + bn * BN + 64 + tn * 4) = hi;
  }
}

// ---------- fp32 -> bf16 conversion ------------------------------------------
__global__ __launch_bounds__(256) void cvt_bf16(const float* __restrict__ in,
                                                unsigned short* __restrict__ out, int n8) {
  const int i = blockIdx.x * 256 + threadIdx.x;
  if (i >= n8) return;
  const float4 a = ((const float4*)in)[2*i];
  const float4 b = ((const float4*)in)[2*i+1];
  u16x8 o;
  o[0]=f2bf(a.x); o[1]=f2bf(a.y); o[2]=f2bf(a.z); o[3]=f2bf(a.w);
  o[4]=f2bf(b.x); o[5]=f2bf(b.y); o[6]=f2bf(b.z); o[7]=f2bf(b.w);
  *(u16x8*)(out + 8*i) = o;
}

// ---------- bf16 MFMA NT GEMM, 128x128 tile, BK=32, double-buffered ----------
// MODE 0 (sim):  C=A0bf*Bw^T, write bf16 to outbf (stride NOUT)
// MODE 1 (wv):   write fp32 to outf + bf16 to outbf (stride NOUT)
// MODE 2 (gate): A = [A0f(fp32, inline cvt) | A1(bf16)]; out = sigmoid(acc+bg)*projf
template<int KTOT, int NOUT, int MODE>
__global__ __launch_bounds__(256) void mfma_nt(
    const unsigned short* __restrict__ A0bf,
    const float* __restrict__ A0f,
    const unsigned short* __restrict__ A1,
    const unsigned short* __restrict__ Bw,
    const float* __restrict__ bg,
    const float* __restrict__ projf,
    float* __restrict__ outf,
    unsigned short* __restrict__ outbf) {
  __shared__ __align__(16) unsigned short As[2][128 * 32];
  __shared__ __align__(16) unsigned short Bs[2][128 * 32];
  const int tid = threadIdx.x;
  const int wv = tid >> 6, l = tid & 63;
  const int bn = blockIdx.x, bm = blockIdx.y;
  const int wr = wv >> 1, wc = wv & 1;
  const int lane16 = l & 15, lhi = l >> 4;

  f32x4 acc[4][4];
#pragma unroll
  for (int mi = 0; mi < 4; mi++)
#pragma unroll
    for (int nj = 0; nj < 4; nj++)
#pragma unroll
      for (int r = 0; r < 4; r++) acc[mi][nj][r] = 0.0f;

  auto stage = [&](int buf, int t) {
    const int k0 = t * 32;
#pragma unroll
    for (int h = 0; h < 2; ++h) {
      const int p = tid + 256 * h;          // chunk index 0..511
      const int r = p >> 2, c = p & 3;
      const int q = k0 + 8 * (c ^ ((r >> 1) & 3));
      if constexpr (MODE == 2) {
        if (k0 < 512) {  // query half: fp32 load + inline cvt + ds_write
          const float* asrcF = A0f + (size_t)(bm * 128 + r) * 512 + q;
          const float4 f0 = *(const float4*)asrcF;
          const float4 f1 = *(const float4*)(asrcF + 4);
          u16x8 o;
          o[0]=f2bf(f0.x); o[1]=f2bf(f0.y); o[2]=f2bf(f0.z); o[3]=f2bf(f0.w);
          o[4]=f2bf(f1.x); o[5]=f2bf(f1.y); o[6]=f2bf(f1.z); o[7]=f2bf(f1.w);
          *(u16x8*)&As[buf][(size_t)p * 8] = o;
        } else {         // proj half: bf16 async
          const unsigned short* asrc = A1 + (size_t)(bm * 128 + r) * 512 + (q - 512);
          GLDS16(asrc, &As[buf][(4 * h + wv) * 512]);
        }
      } else {
        const unsigned short* asrc = A0bf + (size_t)(bm * 128 + r) * 512 + q;
        GLDS16(asrc, &As[buf][(4 * h + wv) * 512]);
      }
      const unsigned short* bsrc = Bw + (size_t)(bn * 128 + r) * KTOT + q;
      GLDS16(bsrc, &Bs[buf][(4 * h + wv) * 512]);
    }
  };

  auto compute = [&](int buf) {
    const int achunk = lhi ^ ((lane16 >> 1) & 3);
    bf16x8 af[4], bfr[4];
#pragma unroll
    for (int mi = 0; mi < 4; ++mi)
      af[mi] = *(const bf16x8*)&As[buf][(wr * 64 + mi * 16 + lane16) * 32 + achunk * 8];
#pragma unroll
    for (int nj = 0; nj < 4; ++nj)
      bfr[nj] = *(const bf16x8*)&Bs[buf][(wc * 64 + nj * 16 + lane16) * 32 + achunk * 8];
#pragma unroll
    for (int mi = 0; mi < 4; ++mi)
#pragma unroll
      for (int nj = 0; nj < 4; ++nj)
        acc[mi][nj] = __builtin_amdgcn_mfma_f32_16x16x32_bf16(af[mi], bfr[nj], acc[mi][nj], 0, 0, 0);
  };

  const int NT = KTOT / 32;
  stage(0, 0);
  __syncthreads();
  for (int t = 0; t < NT - 1; ++t) {
    stage((t + 1) & 1, t + 1);
    compute(t & 1);
    __syncthreads();
  }
  compute((NT - 1) & 1);

  const int rowb = bm * 128 + wr * 64 + (lhi << 2);
  const int colb = bn * 128 + wc * 64 + lane16;
#pragma unroll
  for (int mi = 0; mi < 4; ++mi) {
#pragma unroll
    for (int nj = 0; nj < 4; ++nj) {
      const int col = colb + nj * 16;
#pragma unroll
      for (int r = 0; r < 4; ++r) {
        const int row = rowb + mi * 16 + r;
        const size_t o = (size_t)row * NOUT + col;
        const float v = acc[mi][nj][r];
        if constexpr (MODE == 2) {
          const float x = v + bg[col];
          const float g = 1.0f / (1.0f + __expf(-x));
          outf[o] = g * projf[o];
        } else if constexpr (MODE == 1) {
          outf[o]  = v;
          outbf[o] = f2bf(v);
        } else {
          outbf[o] = f2bf(v);
        }
      }
    }
  }
}

// ---------- coarse top-4 + candidates + fp32 rescore + softmax + gather ------
__global__ __launch_bounds__(256) void topk_rescore_gather(
    const unsigned short* __restrict__ simbf,
    const float* __restrict__ qF,
    const float* __restrict__ invq,
    const float* __restrict__ keysN,
    const float* __restrict__ vals,
    unsigned short* __restrict__ retr) {
  const int b   = blockIdx.x;
  const int tid = threadIdx.x;
  __shared__ float sv[E_];
  __shared__ float qrow[D_];
  __shared__ float rv[256];
  __shared__ int   ri[256];
  __shared__ int   s_cand[MAXC];
  __shared__ float s_rs[MAXC];
  __shared__ int   s_cnt;
  __shared__ float s_wb[4];
  __shared__ int   s_ib[4];

  // load coarse sim row + q row
  const ushort4 u4 = ((const ushort4*)(simbf + (size_t)b * E_))[tid];
  sv[4*tid+0] = bf2f(u4.x); sv[4*tid+1] = bf2f(u4.y);
  sv[4*tid+2] = bf2f(u4.z); sv[4*tid+3] = bf2f(u4.w);
  qrow[tid]       = qF[(size_t)b * D_ + tid];
  qrow[256 + tid] = qF[(size_t)b * D_ + 256 + tid];
  if (tid == 0) s_cnt = 4;
  __syncthreads();

  // 4 coarse argmax passes
  float t4val = 0.0f;
  for (int k = 0; k < 4; k++) {
    float bv = -3.402823466e38f;
    int   bi = 0x7fffffff;
#pragma unroll
    for (int m = 0; m < 4; m++) {
      const int i = tid + 256 * m;
      const float v = sv[i];
      if (v > bv || (v == bv && i < bi)) { bv = v; bi = i; }
    }
    rv[tid] = bv; ri[tid] = bi;
    __syncthreads();
    for (int s = 128; s > 0; s >>= 1) {
      if (tid < s) {
        const float v2 = rv[tid + s];
        const int   i2 = ri[tid + s];
        if (v2 > rv[tid] || (v2 == rv[tid] && i2 < ri[tid])) { rv[tid] = v2; ri[tid] = i2; }
      }
      __syncthreads();
    }
    if (tid == 0) {
      s_cand[k] = ri[0];
      sv[ri[0]] = -3.402823466e38f;
      if (k == 3) rv[1] = rv[0];      // stash 4th value for broadcast
    }
    __syncthreads();
    if (k == 3) t4val = rv[1];
  }

  // collect extra candidates within margin of coarse 4th value
  const float thr = t4val - 0.004f;
#pragma unroll
  for (int m = 0; m < 4; m++) {
    const int i = tid + 256 * m;
    if (sv[i] >= thr) {
      const int pos = atomicAdd(&s_cnt, 1);
      if (pos < MAXC) s_cand[pos] = i;
    }
  }
  __syncthreads();
  const int n = min(s_cnt, MAXC);

  // fp32 rescore: sim[c] = dot(q, keysN[c]) * invq[b]
  const int w = tid >> 6, l = tid & 63;
  for (int ci = w; ci < n; ci += 4) {
    const float* kr = keysN + (size_t)s_cand[ci] * D_;
    float p = 0.0f;
#pragma unroll
    for (int j = 0; j < 8; j++) p = fmaf(qrow[l * 8 + j], kr[l * 8 + j], p);
#pragma unroll
    for (int off = 32; off > 0; off >>= 1) p += __shfl_xor(p, off, 64);
    if (l == 0) s_rs[ci] = p * invq[b];
  }
  __syncthreads();

  // exact top-4 by (value desc, index asc) + softmax weights
  if (tid == 0) {
    bool used[MAXC];
    for (int c = 0; c < n; c++) used[c] = false;
    float tv[4]; int ti[4];
    for (int k = 0; k < 4; k++) {
      float bv = -3.402823466e38f; int bi = 0x7fffffff; int bc = 0;
      for (int c = 0; c < n; c++) {
        if (used[c]) continue;
        const float v = s_rs[c]; const int i = s_cand[c];
        if (v > bv || (v == bv && i < bi)) { bv = v; bi = i; bc = c; }
      }
      used[bc] = true; tv[k] = bv; ti[k] = bi;
    }
    float mx = 5.0f * tv[0];
    for (int k = 1; k < 4; k++) mx = fmaxf(mx, 5.0f * tv[k]);
    float ws = 0.0f, wk[4];
    for (int k = 0; k < 4; k++) { wk[k] = expf(5.0f * tv[k] - mx); ws += wk[k]; }
    const float wi = 1.0f / ws;
    for (int k = 0; k < 4; k++) { s_wb[k] = wk[k] * wi; s_ib[k] = ti[k]; }
  }
  __syncthreads();

  // gather: retrieved = sum_k w[k] * vals[idx[k]]  -> bf16
  const float w0 = s_wb[0], w1 = s_wb[1], w2 = s_wb[2], w3 = s_wb[3];
  const int   i0 = s_ib[0], i1 = s_ib[1], i2 = s_ib[2], i3 = s_ib[3];
  const int c = 2 * tid;
  const float2 v0 = *(const float2*)(vals + (size_t)i0 * D_ + c);
  const float2 v1 = *(const float2*)(vals + (size_t)i1 * D_ + c);
  const float2 v2 = *(const float2*)(vals + (size_t)i2 * D_ + c);
  const float2 v3 = *(const float2*)(vals + (size_t)i3 * D_ + c);
  ushort2 o;
  o.x = f2bf(w0*v0.x + w1*v1.x + w2*v2.x + w3*v3.x);
  o.y = f2bf(w0*v0.y + w1*v1.y + w2*v2.y + w3*v3.y);
  *(ushort2*)(retr + (size_t)b * D_ + c) = o;
}

extern "C" void kernel_launch(void* const* d_in, const int* in_sizes, int n_in,
                              void* d_out, int out_size, void* d_ws, size_t ws_size,
                              hipStream_t stream) {
  (void)in_sizes; (void)n_in; (void)out_size; (void)ws_size;
  const float* query = (const float*)d_in[0];
  const float* keys  = (const float*)d_in[1];
  const float* vals  = (const float*)d_in[2];
  const float* Wq    = (const float*)d_in[3];
  const float* Wv    = (const float*)d_in[4];
  const float* Wg    = (const float*)d_in[5];
  const float* bg    = (const float*)d_in[6];
  float* out = (float*)d_out;

  char* ws = (char*)d_ws;
  const size_t M = 1u << 20;
  float*          qF      = (float*)(ws);                 // [0,32M)
  float*          projF   = (float*)(ws);                 // overlay after topk
  unsigned short* sim_bf  = (unsigned short*)(ws + 32*M); // [32M,64M)
  unsigned short* proj_bf = (unsigned short*)(ws + 32*M); // overlay after topk
  unsigned short* qn_bf   = (unsigned short*)(ws + 64*M); // [64M,80M)
  unsigned short* retr_bf = (unsigned short*)(ws + 64*M); // overlay after sim
  float*          keysN   = (float*)(ws + 80*M);          // 2 MB
  unsigned short* kn_bf   = (unsigned short*)(ws + 82*M); // 1 MB
  unsigned short* Wv_bf   = (unsigned short*)(ws + 83*M); // 0.5 MB
  unsigned short* Wg_bf   = (unsigned short*)(ws + 84*M); // 1 MB
  float*          invq    = (float*)(ws + 85*M);          // 64 KB

  l2norm_keys<<<E_, 64, 0, stream>>>(keys, keysN, kn_bf);
  sgemm_v2<<<dim3(D_ / BN, B_ / BM), 256, 0, stream>>>(query, Wq, qF, B_, D_, D_);
  l2norm_q<<<B_, 64, 0, stream>>>(qF, qn_bf, invq);
  cvt_bf16<<<(D_ * D_ / 8 + 255) / 256, 256, 0, stream>>>(Wv, Wv_bf, D_ * D_ / 8);
  cvt_bf16<<<(D_ * 2 * D_ / 8 + 255) / 256, 256, 0, stream>>>(Wg, Wg_bf, D_ * 2 * D_ / 8);

  // coarse sim (bf16): [B,E]
  mfma_nt<512, 1024, 0><<<dim3(E_ / 128, B_ / 128), 256, 0, stream>>>(
      qn_bf, nullptr, nullptr, kn_bf, nullptr, nullptr, nullptr, sim_bf);

  topk_rescore_gather<<<B_, 256, 0, stream>>>(sim_bf, qF, invq, keysN, vals, retr_bf);

  // proj = retrieved @ Wv^T  (fp32 + bf16 outputs)
  mfma_nt<512, 512, 1><<<dim3(D_ / 128, B_ / 128), 256, 0, stream>>>(
      retr_bf, nullptr, nullptr, Wv_bf, nullptr, nullptr, projF, proj_bf);

  // out = sigmoid([query|proj] @ Wg^T + bg) * proj
  mfma_nt<1024, 512, 2><<<dim3(D_ / 128, B_ / 128), 256, 0, stream>>>(
      nullptr, query, proj_bf, Wg_bf, bg, projF, out, nullptr);
}

// Round 4
// 301.817 us; speedup vs baseline: 3.1044x; 1.7049x over previous
//
#include <hip/hip_runtime.h>
#include <hip/hip_bf16.h>
#include <math.h>

// EpisodicMemory round 4.
// fp32 exact path: Wq GEMM (b128-LDS sgemm) -> q; wave-parallel rescore topk.
// bf16 MFMA: coarse sim, Wv GEMM, gate GEMM.
// ws layout (85 MB used, 98 MB proven):
//   [0,32M)   q fp32 (Wq->topk)          -> projF (Wv->gate)
//   [32M,64M) sim_bf (sim->topk)         -> proj_bf@32M (Wv->gate)
//   [64M,80M) qn_bf (l2q->sim)           -> retr_bf (topk->Wv)
//   [80M,82M) keysN fp32   [82M,83M) kn_bf   [83M,83.5M) Wv_bf
//   [84M,85M) Wg_bf        [85M,+64K) invq

#define B_ 16384
#define D_ 512
#define E_ 1024

typedef __attribute__((ext_vector_type(8))) short bf16x8;
typedef __attribute__((ext_vector_type(4))) float f32x4;
typedef __attribute__((ext_vector_type(8))) unsigned short u16x8;

__device__ __forceinline__ unsigned short f2bf(float f) {
  unsigned u = __builtin_bit_cast(unsigned, f);
  unsigned r = (u + 0x7fffu + ((u >> 16) & 1u)) >> 16;
  return (unsigned short)r;
}
__device__ __forceinline__ float bf2f(unsigned short u) {
  return __builtin_bit_cast(float, (unsigned)u << 16);
}

#define GLDS16(g, l)                                                          \
  __builtin_amdgcn_global_load_lds(                                           \
      (const __attribute__((address_space(1))) void*)(g),                     \
      (__attribute__((address_space(3))) void*)(l), 16, 0, 0)

// ---------- L2 normalize keys: fp32 out + bf16 out ---------------------------
__global__ __launch_bounds__(64) void l2norm_keys(const float* __restrict__ in,
                                                  float* __restrict__ outF,
                                                  unsigned short* __restrict__ outBF) {
  const int row  = blockIdx.x;
  const int lane = threadIdx.x;
  const float4* p4 = (const float4*)(in + (size_t)row * D_);
  float4 a = p4[lane];
  float4 b = p4[lane + 64];
  float ss = a.x*a.x + a.y*a.y + a.z*a.z + a.w*a.w
           + b.x*b.x + b.y*b.y + b.z*b.z + b.w*b.w;
#pragma unroll
  for (int off = 32; off > 0; off >>= 1) ss += __shfl_xor(ss, off, 64);
  const float inv = 1.0f / fmaxf(sqrtf(ss), 1e-12f);
  a.x *= inv; a.y *= inv; a.z *= inv; a.w *= inv;
  b.x *= inv; b.y *= inv; b.z *= inv; b.w *= inv;
  float4* o4 = (float4*)(outF + (size_t)row * D_);
  o4[lane]      = a;
  o4[lane + 64] = b;
  ushort4 ua, ub;
  ua.x=f2bf(a.x); ua.y=f2bf(a.y); ua.z=f2bf(a.z); ua.w=f2bf(a.w);
  ub.x=f2bf(b.x); ub.y=f2bf(b.y); ub.z=f2bf(b.z); ub.w=f2bf(b.w);
  *(ushort4*)(outBF + (size_t)row * D_ + 4*lane)       = ua;
  *(ushort4*)(outBF + (size_t)row * D_ + 256 + 4*lane) = ub;
}

// ---------- L2 normalize q: bf16 normalized out + inv-norm -------------------
__global__ __launch_bounds__(64) void l2norm_q(const float* __restrict__ in,
                                               unsigned short* __restrict__ outBF,
                                               float* __restrict__ invq) {
  const int row  = blockIdx.x;
  const int lane = threadIdx.x;
  const float4* p4 = (const float4*)(in + (size_t)row * D_);
  float4 a = p4[lane];
  float4 b = p4[lane + 64];
  float ss = a.x*a.x + a.y*a.y + a.z*a.z + a.w*a.w
           + b.x*b.x + b.y*b.y + b.z*b.z + b.w*b.w;
#pragma unroll
  for (int off = 32; off > 0; off >>= 1) ss += __shfl_xor(ss, off, 64);
  const float inv = 1.0f / fmaxf(sqrtf(ss), 1e-12f);
  ushort4 ua, ub;
  ua.x=f2bf(a.x*inv); ua.y=f2bf(a.y*inv); ua.z=f2bf(a.z*inv); ua.w=f2bf(a.w*inv);
  ub.x=f2bf(b.x*inv); ub.y=f2bf(b.y*inv); ub.z=f2bf(b.z*inv); ub.w=f2bf(b.w*inv);
  *(ushort4*)(outBF + (size_t)row * D_ + 4*lane)       = ua;
  *(ushort4*)(outBF + (size_t)row * D_ + 256 + 4*lane) = ub;
  if (lane == 0) invq[row] = inv;
}

// ---------- fp32 NT SGEMM, b128 LDS reads: C[M,N]=A[M,K]*B[N,K]^T ------------
#define BM 128
#define BN 128
#define BKf 8
__global__ __launch_bounds__(256) void sgemm_v2(const float* __restrict__ A,
                                                const float* __restrict__ Bm,
                                                float* __restrict__ C,
                                                int M, int N, int K) {
  __shared__ float As[BKf][BM];
  __shared__ float Bs[BKf][BN];
  const int tid = threadIdx.x;
  const int bn = blockIdx.x, bm = blockIdx.y;
  const int tm = (tid >> 4) & 15, tn = tid & 15;
  const int lrow = tid >> 1, lk4 = (tid & 1) * 4;
  const float* Ap = A  + (size_t)(bm * BM + lrow) * K + lk4;
  const float* Bp = Bm + (size_t)(bn * BN + lrow) * K + lk4;

  float acc[8][8];
#pragma unroll
  for (int i = 0; i < 8; i++)
#pragma unroll
    for (int j = 0; j < 8; j++) acc[i][j] = 0.0f;

  for (int k0 = 0; k0 < K; k0 += BKf) {
    const float4 av = *(const float4*)(Ap + k0);
    const float4 bv = *(const float4*)(Bp + k0);
    As[lk4 + 0][lrow] = av.x; As[lk4 + 1][lrow] = av.y;
    As[lk4 + 2][lrow] = av.z; As[lk4 + 3][lrow] = av.w;
    Bs[lk4 + 0][lrow] = bv.x; Bs[lk4 + 1][lrow] = bv.y;
    Bs[lk4 + 2][lrow] = bv.z; Bs[lk4 + 3][lrow] = bv.w;
    __syncthreads();
#pragma unroll
    for (int k = 0; k < BKf; k++) {
      const float4 alo = *(const float4*)&As[k][tm * 4];
      const float4 ahi = *(const float4*)&As[k][64 + tm * 4];
      const float4 blo = *(const float4*)&Bs[k][tn * 4];
      const float4 bhi = *(const float4*)&Bs[k][64 + tn * 4];
      const float a[8] = {alo.x, alo.y, alo.z, alo.w, ahi.x, ahi.y, ahi.z, ahi.w};
      const float b[8] = {blo.x, blo.y, blo.z, blo.w, bhi.x, bhi.y, bhi.z, bhi.w};
#pragma unroll
      for (int i = 0; i < 8; i++)
#pragma unroll
        for (int j = 0; j < 8; j++) acc[i][j] = fmaf(a[i], b[j], acc[i][j]);
    }
    __syncthreads();
  }
#pragma unroll
  for (int i = 0; i < 8; i++) {
    const int row = bm * BM + (i >> 2) * 64 + tm * 4 + (i & 3);
    float4 lo = make_float4(acc[i][0], acc[i][1], acc[i][2], acc[i][3]);
    float4 hi = make_float4(acc[i][4], acc[i][5], acc[i][6], acc[i][7]);
    *(float4*)(C + (size_t)row * N + bn * BN + tn * 4)      = lo;
    *(float4*)(C + (size_t)row * N + bn * BN + 64 + tn * 4) = hi;
  }
}

// ---------- fp32 -> bf16 conversion ------------------------------------------
__global__ __launch_bounds__(256) void cvt_bf16(const float* __restrict__ in,
                                                unsigned short* __restrict__ out, int n8) {
  const int i = blockIdx.x * 256 + threadIdx.x;
  if (i >= n8) return;
  const float4 a = ((const float4*)in)[2*i];
  const float4 b = ((const float4*)in)[2*i+1];
  u16x8 o;
  o[0]=f2bf(a.x); o[1]=f2bf(a.y); o[2]=f2bf(a.z); o[3]=f2bf(a.w);
  o[4]=f2bf(b.x); o[5]=f2bf(b.y); o[6]=f2bf(b.z); o[7]=f2bf(b.w);
  *(u16x8*)(out + 8*i) = o;
}

// ---------- bf16 MFMA NT GEMM, 128x128 tile, BK=32, double-buffered ----------
template<int KTOT, int NOUT, int MODE>
__global__ __launch_bounds__(256) void mfma_nt(
    const unsigned short* __restrict__ A0bf,
    const float* __restrict__ A0f,
    const unsigned short* __restrict__ A1,
    const unsigned short* __restrict__ Bw,
    const float* __restrict__ bg,
    const float* __restrict__ projf,
    float* __restrict__ outf,
    unsigned short* __restrict__ outbf) {
  __shared__ __align__(16) unsigned short As[2][128 * 32];
  __shared__ __align__(16) unsigned short Bs[2][128 * 32];
  const int tid = threadIdx.x;
  const int wv = tid >> 6, l = tid & 63;
  const int bn = blockIdx.x, bm = blockIdx.y;
  const int wr = wv >> 1, wc = wv & 1;
  const int lane16 = l & 15, lhi = l >> 4;

  f32x4 acc[4][4];
#pragma unroll
  for (int mi = 0; mi < 4; mi++)
#pragma unroll
    for (int nj = 0; nj < 4; nj++)
#pragma unroll
      for (int r = 0; r < 4; r++) acc[mi][nj][r] = 0.0f;

  auto stage = [&](int buf, int t) {
    const int k0 = t * 32;
#pragma unroll
    for (int h = 0; h < 2; ++h) {
      const int p = tid + 256 * h;          // chunk index 0..511
      const int r = p >> 2, c = p & 3;
      const int q = k0 + 8 * (c ^ ((r >> 1) & 3));
      if constexpr (MODE == 2) {
        if (k0 < 512) {  // query half: fp32 load + inline cvt + ds_write
          const float* asrcF = A0f + (size_t)(bm * 128 + r) * 512 + q;
          const float4 f0 = *(const float4*)asrcF;
          const float4 f1 = *(const float4*)(asrcF + 4);
          u16x8 o;
          o[0]=f2bf(f0.x); o[1]=f2bf(f0.y); o[2]=f2bf(f0.z); o[3]=f2bf(f0.w);
          o[4]=f2bf(f1.x); o[5]=f2bf(f1.y); o[6]=f2bf(f1.z); o[7]=f2bf(f1.w);
          *(u16x8*)&As[buf][(size_t)p * 8] = o;
        } else {         // proj half: bf16 async
          const unsigned short* asrc = A1 + (size_t)(bm * 128 + r) * 512 + (q - 512);
          GLDS16(asrc, &As[buf][(4 * h + wv) * 512]);
        }
      } else {
        const unsigned short* asrc = A0bf + (size_t)(bm * 128 + r) * 512 + q;
        GLDS16(asrc, &As[buf][(4 * h + wv) * 512]);
      }
      const unsigned short* bsrc = Bw + (size_t)(bn * 128 + r) * KTOT + q;
      GLDS16(bsrc, &Bs[buf][(4 * h + wv) * 512]);
    }
  };

  auto compute = [&](int buf) {
    const int achunk = lhi ^ ((lane16 >> 1) & 3);
    bf16x8 af[4], bfr[4];
#pragma unroll
    for (int mi = 0; mi < 4; ++mi)
      af[mi] = *(const bf16x8*)&As[buf][(wr * 64 + mi * 16 + lane16) * 32 + achunk * 8];
#pragma unroll
    for (int nj = 0; nj < 4; ++nj)
      bfr[nj] = *(const bf16x8*)&Bs[buf][(wc * 64 + nj * 16 + lane16) * 32 + achunk * 8];
#pragma unroll
    for (int mi = 0; mi < 4; ++mi)
#pragma unroll
      for (int nj = 0; nj < 4; ++nj)
        acc[mi][nj] = __builtin_amdgcn_mfma_f32_16x16x32_bf16(af[mi], bfr[nj], acc[mi][nj], 0, 0, 0);
  };

  const int NT = KTOT / 32;
  stage(0, 0);
  __syncthreads();
  for (int t = 0; t < NT - 1; ++t) {
    stage((t + 1) & 1, t + 1);
    compute(t & 1);
    __syncthreads();
  }
  compute((NT - 1) & 1);

  const int rowb = bm * 128 + wr * 64 + (lhi << 2);
  const int colb = bn * 128 + wc * 64 + lane16;
#pragma unroll
  for (int mi = 0; mi < 4; ++mi) {
#pragma unroll
    for (int nj = 0; nj < 4; ++nj) {
      const int col = colb + nj * 16;
#pragma unroll
      for (int r = 0; r < 4; ++r) {
        const int row = rowb + mi * 16 + r;
        const size_t o = (size_t)row * NOUT + col;
        const float v = acc[mi][nj][r];
        if constexpr (MODE == 2) {
          const float x = v + bg[col];
          const float g = 1.0f / (1.0f + __expf(-x));
          outf[o] = g * projf[o];
        } else if constexpr (MODE == 1) {
          outf[o]  = v;
          outbf[o] = f2bf(v);
        } else {
          outbf[o] = f2bf(v);
        }
      }
    }
  }
}

// ---------- wave-per-row: coarse top-4 + margin rescore + softmax + gather ---
// One wave per row; zero LDS; zero __syncthreads. Lane l holds sim[16l..16l+16)
// and q[8l..8l+8). Coarse winners + margin candidates rescored in fp32
// (keysN is L2-resident); exact top-4 kept as sorted regs with (v desc, i asc).
__global__ __launch_bounds__(256) void topk_rescore_gather(
    const unsigned short* __restrict__ simbf,
    const float* __restrict__ qF,
    const float* __restrict__ invq,
    const float* __restrict__ keysN,
    const float* __restrict__ vals,
    unsigned short* __restrict__ retr) {
  const int w = threadIdx.x >> 6, l = threadIdx.x & 63;
  const int b = blockIdx.x * 4 + w;
  const float NEG = -3.402823466e38f;

  // sim row: 16 bf16 per lane -> fp32 regs (fully unrolled, stays in VGPRs)
  const u16x8* sp = (const u16x8*)(simbf + (size_t)b * E_ + 16 * l);
  const u16x8 s0 = sp[0], s1 = sp[1];
  float v[16];
#pragma unroll
  for (int j = 0; j < 8; j++) { v[j] = bf2f((unsigned short)s0[j]); v[8 + j] = bf2f((unsigned short)s1[j]); }

  // q row: 8 floats per lane
  const float4* qp = (const float4*)(qF + (size_t)b * D_ + 8 * l);
  const float4 q0 = qp[0], q1 = qp[1];

  // fp32 rescore of key[idx]: all 64 lanes cooperate, result in all lanes
  auto score = [&](int idx) -> float {
    const float4* kp = (const float4*)(keysN + (size_t)idx * D_ + 8 * l);
    const float4 k0 = kp[0], k1 = kp[1];
    float p = q0.x * k0.x;
    p = fmaf(q0.y, k0.y, p); p = fmaf(q0.z, k0.z, p); p = fmaf(q0.w, k0.w, p);
    p = fmaf(q1.x, k1.x, p); p = fmaf(q1.y, k1.y, p);
    p = fmaf(q1.z, k1.z, p); p = fmaf(q1.w, k1.w, p);
#pragma unroll
    for (int off = 32; off > 0; off >>= 1) p += __shfl_xor(p, off, 64);
    return p;
  };

  // exact top-4 sorted regs, comparator (v desc, i asc)
  float rv0 = NEG, rv1 = NEG, rv2 = NEG, rv3 = NEG;
  int   ri0 = 0x7fffffff, ri1 = 0x7fffffff, ri2 = 0x7fffffff, ri3 = 0x7fffffff;
  auto ins = [&](float nv, int ni) {
    if (nv > rv0 || (nv == rv0 && ni < ri0)) {
      rv3 = rv2; ri3 = ri2; rv2 = rv1; ri2 = ri1; rv1 = rv0; ri1 = ri0; rv0 = nv; ri0 = ni;
    } else if (nv > rv1 || (nv == rv1 && ni < ri1)) {
      rv3 = rv2; ri3 = ri2; rv2 = rv1; ri2 = ri1; rv1 = nv; ri1 = ni;
    } else if (nv > rv2 || (nv == rv2 && ni < ri2)) {
      rv3 = rv2; ri3 = ri2; rv2 = nv; ri2 = ni;
    } else if (nv > rv3 || (nv == rv3 && ni < ri3)) {
      rv3 = nv; ri3 = ni;
    }
  };

  // 4 coarse argmax passes (kill via bitmask, no runtime reg-array writes)
  unsigned killed = 0;
  float t4 = NEG;
#pragma unroll
  for (int k = 0; k < 4; k++) {
    float bv = NEG; int bs = 0;
#pragma unroll
    for (int j = 0; j < 16; j++) {
      const float vj = ((killed >> j) & 1u) ? NEG : v[j];
      if (vj > bv) { bv = vj; bs = j; }
    }
    int bi = l * 16 + bs;
#pragma unroll
    for (int off = 32; off > 0; off >>= 1) {
      const float ov = __shfl_xor(bv, off, 64);
      const int   oi = __shfl_xor(bi, off, 64);
      if (ov > bv || (ov == bv && oi < bi)) { bv = ov; bi = oi; }
    }
    if ((bi >> 4) == l) killed |= 1u << (bi & 15);
    ins(score(bi), bi);
    t4 = bv;  // after last pass: coarse 4th value
  }

  // margin candidates: uniform ballot + ctz walk (deterministic, no cap)
  const float thr = t4 - 0.004f;
#pragma unroll
  for (int s = 0; s < 16; s++) {
    const bool pred = (((killed >> s) & 1u) == 0u) && (v[s] >= thr);
    unsigned long long m = __ballot(pred);
    while (m) {
      const int ln = __builtin_ctzll(m);
      m &= m - 1;
      const int idx = ln * 16 + s;
      ins(score(idx), idx);
    }
  }

  // apply inv-norm (positive scale: ranking unchanged), softmax
  const float iq = invq[b];
  const float f0 = rv0 * iq, f1 = rv1 * iq, f2 = rv2 * iq, f3 = rv3 * iq;
  const float mx = 5.0f * f0;
  const float e0 = expf(5.0f * f0 - mx), e1 = expf(5.0f * f1 - mx);
  const float e2 = expf(5.0f * f2 - mx), e3 = expf(5.0f * f3 - mx);
  const float wi = 1.0f / (e0 + e1 + e2 + e3);
  const float w0 = e0 * wi, w1 = e1 * wi, w2 = e2 * wi, w3 = e3 * wi;

  // gather: 8 cols per lane, vals L2-resident
  const float4* v0p = (const float4*)(vals + (size_t)ri0 * D_ + 8 * l);
  const float4* v1p = (const float4*)(vals + (size_t)ri1 * D_ + 8 * l);
  const float4* v2p = (const float4*)(vals + (size_t)ri2 * D_ + 8 * l);
  const float4* v3p = (const float4*)(vals + (size_t)ri3 * D_ + 8 * l);
  const float4 a0 = v0p[0], b0 = v0p[1];
  const float4 a1 = v1p[0], b1 = v1p[1];
  const float4 a2 = v2p[0], b2 = v2p[1];
  const float4 a3 = v3p[0], b3 = v3p[1];
  u16x8 o;
  o[0] = f2bf(w0 * a0.x + w1 * a1.x + w2 * a2.x + w3 * a3.x);
  o[1] = f2bf(w0 * a0.y + w1 * a1.y + w2 * a2.y + w3 * a3.y);
  o[2] = f2bf(w0 * a0.z + w1 * a1.z + w2 * a2.z + w3 * a3.z);
  o[3] = f2bf(w0 * a0.w + w1 * a1.w + w2 * a2.w + w3 * a3.w);
  o[4] = f2bf(w0 * b0.x + w1 * b1.x + w2 * b2.x + w3 * b3.x);
  o[5] = f2bf(w0 * b0.y + w1 * b1.y + w2 * b2.y + w3 * b3.y);
  o[6] = f2bf(w0 * b0.z + w1 * b1.z + w2 * b2.z + w3 * b3.z);
  o[7] = f2bf(w0 * b0.w + w1 * b1.w + w2 * b2.w + w3 * b3.w);
  *(u16x8*)(retr + (size_t)b * D_ + 8 * l) = o;
}

extern "C" void kernel_launch(void* const* d_in, const int* in_sizes, int n_in,
                              void* d_out, int out_size, void* d_ws, size_t ws_size,
                              hipStream_t stream) {
  (void)in_sizes; (void)n_in; (void)out_size; (void)ws_size;
  const float* query = (const float*)d_in[0];
  const float* keys  = (const float*)d_in[1];
  const float* vals  = (const float*)d_in[2];
  const float* Wq    = (const float*)d_in[3];
  const float* Wv    = (const float*)d_in[4];
  const float* Wg    = (const float*)d_in[5];
  const float* bg    = (const float*)d_in[6];
  float* out = (float*)d_out;

  char* ws = (char*)d_ws;
  const size_t M = 1u << 20;
  float*          qF      = (float*)(ws);                 // [0,32M)
  float*          projF   = (float*)(ws);                 // overlay after topk
  unsigned short* sim_bf  = (unsigned short*)(ws + 32*M); // [32M,64M)
  unsigned short* proj_bf = (unsigned short*)(ws + 32*M); // overlay after topk
  unsigned short* qn_bf   = (unsigned short*)(ws + 64*M); // [64M,80M)
  unsigned short* retr_bf = (unsigned short*)(ws + 64*M); // overlay after sim
  float*          keysN   = (float*)(ws + 80*M);          // 2 MB
  unsigned short* kn_bf   = (unsigned short*)(ws + 82*M); // 1 MB
  unsigned short* Wv_bf   = (unsigned short*)(ws + 83*M); // 0.5 MB
  unsigned short* Wg_bf   = (unsigned short*)(ws + 84*M); // 1 MB
  float*          invq    = (float*)(ws + 85*M);          // 64 KB

  l2norm_keys<<<E_, 64, 0, stream>>>(keys, keysN, kn_bf);
  sgemm_v2<<<dim3(D_ / BN, B_ / BM), 256, 0, stream>>>(query, Wq, qF, B_, D_, D_);
  l2norm_q<<<B_, 64, 0, stream>>>(qF, qn_bf, invq);
  cvt_bf16<<<(D_ * D_ / 8 + 255) / 256, 256, 0, stream>>>(Wv, Wv_bf, D_ * D_ / 8);
  cvt_bf16<<<(D_ * 2 * D_ / 8 + 255) / 256, 256, 0, stream>>>(Wg, Wg_bf, D_ * 2 * D_ / 8);

  // coarse sim (bf16): [B,E]
  mfma_nt<512, 1024, 0><<<dim3(E_ / 128, B_ / 128), 256, 0, stream>>>(
      qn_bf, nullptr, nullptr, kn_bf, nullptr, nullptr, nullptr, sim_bf);

  topk_rescore_gather<<<B_ / 4, 256, 0, stream>>>(sim_bf, qF, invq, keysN, vals, retr_bf);

  // proj = retrieved @ Wv^T  (fp32 + bf16 outputs)
  mfma_nt<512, 512, 1><<<dim3(D_ / 128, B_ / 128), 256, 0, stream>>>(
      retr_bf, nullptr, nullptr, Wv_bf, nullptr, nullptr, projF, proj_bf);

  // out = sigmoid([query|proj] @ Wg^T + bg) * proj
  mfma_nt<1024, 512, 2><<<dim3(D_ / 128, B_ / 128), 256, 0, stream>>>(
      nullptr, query, proj_bf, Wg_bf, bg, projF, out, nullptr);
}

// Round 5
// 298.177 us; speedup vs baseline: 3.1423x; 1.0122x over previous
//
#include <hip/hip_runtime.h>
#include <hip/hip_bf16.h>
#include <math.h>

// EpisodicMemory round 5.
// Key idea: q.k == query.(Wq^T k) -> fp32 rescore via K' = keysN @ Wq (tiny GEMM).
// The big Wq GEMM moves to bf16 MFMA (only feeds coarse sim + |q|).
// ws layout (<=98 MB):
//   [0,64M)    sim fp32 (MFMA out)    -> projF [0,32M) + proj_bf [32M,48M) after topk
//   [32M,64M)  qF32 (MFMA q out; dead before sim GEMM overwrites)
//   [64M,80M)  qn_bf (l2q->sim)       -> retr_bf overlay (topk->Wv)
//   [80M,81M)  kn_bf    [81M,83M) keysN   [83M,84M) WqT    [84M,86M) Kp
//   [86M,86.5M) Wq_bf   [86.5M,87M) Wv_bf [87M,88M) Wg_bf  [88M,+64K) invq

#define B_ 16384
#define D_ 512
#define E_ 1024

typedef __attribute__((ext_vector_type(8))) short bf16x8;
typedef __attribute__((ext_vector_type(4))) float f32x4;
typedef __attribute__((ext_vector_type(8))) unsigned short u16x8;

__device__ __forceinline__ unsigned short f2bf(float f) {
  unsigned u = __builtin_bit_cast(unsigned, f);
  unsigned r = (u + 0x7fffu + ((u >> 16) & 1u)) >> 16;
  return (unsigned short)r;
}

#define GLDS16(g, l)                                                          \
  __builtin_amdgcn_global_load_lds(                                           \
      (const __attribute__((address_space(1))) void*)(g),                     \
      (__attribute__((address_space(3))) void*)(l), 16, 0, 0)

// ---------- L2 normalize keys: fp32 out + bf16 out ---------------------------
__global__ __launch_bounds__(64) void l2norm_keys(const float* __restrict__ in,
                                                  float* __restrict__ outF,
                                                  unsigned short* __restrict__ outBF) {
  const int row  = blockIdx.x;
  const int lane = threadIdx.x;
  const float4* p4 = (const float4*)(in + (size_t)row * D_);
  float4 a = p4[lane];
  float4 b = p4[lane + 64];
  float ss = a.x*a.x + a.y*a.y + a.z*a.z + a.w*a.w
           + b.x*b.x + b.y*b.y + b.z*b.z + b.w*b.w;
#pragma unroll
  for (int off = 32; off > 0; off >>= 1) ss += __shfl_xor(ss, off, 64);
  const float inv = 1.0f / fmaxf(sqrtf(ss), 1e-12f);
  a.x *= inv; a.y *= inv; a.z *= inv; a.w *= inv;
  b.x *= inv; b.y *= inv; b.z *= inv; b.w *= inv;
  float4* o4 = (float4*)(outF + (size_t)row * D_);
  o4[lane]      = a;
  o4[lane + 64] = b;
  ushort4 ua, ub;
  ua.x=f2bf(a.x); ua.y=f2bf(a.y); ua.z=f2bf(a.z); ua.w=f2bf(a.w);
  ub.x=f2bf(b.x); ub.y=f2bf(b.y); ub.z=f2bf(b.z); ub.w=f2bf(b.w);
  *(ushort4*)(outBF + (size_t)row * D_ + 4*lane)       = ua;
  *(ushort4*)(outBF + (size_t)row * D_ + 256 + 4*lane) = ub;
}

// ---------- L2 normalize q: bf16 normalized out + inv-norm -------------------
__global__ __launch_bounds__(64) void l2norm_q(const float* __restrict__ in,
                                               unsigned short* __restrict__ outBF,
                                               float* __restrict__ invq) {
  const int row  = blockIdx.x;
  const int lane = threadIdx.x;
  const float4* p4 = (const float4*)(in + (size_t)row * D_);
  float4 a = p4[lane];
  float4 b = p4[lane + 64];
  float ss = a.x*a.x + a.y*a.y + a.z*a.z + a.w*a.w
           + b.x*b.x + b.y*b.y + b.z*b.z + b.w*b.w;
#pragma unroll
  for (int off = 32; off > 0; off >>= 1) ss += __shfl_xor(ss, off, 64);
  const float inv = 1.0f / fmaxf(sqrtf(ss), 1e-12f);
  ushort4 ua, ub;
  ua.x=f2bf(a.x*inv); ua.y=f2bf(a.y*inv); ua.z=f2bf(a.z*inv); ua.w=f2bf(a.w*inv);
  ub.x=f2bf(b.x*inv); ub.y=f2bf(b.y*inv); ub.z=f2bf(b.z*inv); ub.w=f2bf(b.w*inv);
  *(ushort4*)(outBF + (size_t)row * D_ + 4*lane)       = ua;
  *(ushort4*)(outBF + (size_t)row * D_ + 256 + 4*lane) = ub;
  if (lane == 0) invq[row] = inv;
}

// ---------- 512x512 fp32 transpose (for WqT) ---------------------------------
__global__ __launch_bounds__(256) void transpose512(const float* __restrict__ in,
                                                    float* __restrict__ out) {
  __shared__ float t[32][33];
  const int tx = threadIdx.x & 31, ty = threadIdx.x >> 5;
  const int bx = blockIdx.x, by = blockIdx.y;
#pragma unroll
  for (int k = 0; k < 4; k++)
    t[ty + 8*k][tx] = in[(size_t)(by*32 + ty + 8*k) * 512 + bx*32 + tx];
  __syncthreads();
#pragma unroll
  for (int k = 0; k < 4; k++)
    out[(size_t)(bx*32 + ty + 8*k) * 512 + by*32 + tx] = t[tx][ty + 8*k];
}

// ---------- fp32 NT SGEMM (for tiny K' GEMM): C[M,N]=A[M,K]*B[N,K]^T ---------
#define BM 128
#define BN 128
#define BKf 8
__global__ __launch_bounds__(256) void sgemm_v2(const float* __restrict__ A,
                                                const float* __restrict__ Bm,
                                                float* __restrict__ C,
                                                int M, int N, int K) {
  __shared__ float As[BKf][BM];
  __shared__ float Bs[BKf][BN];
  const int tid = threadIdx.x;
  const int bn = blockIdx.x, bm = blockIdx.y;
  const int tm = (tid >> 4) & 15, tn = tid & 15;
  const int lrow = tid >> 1, lk4 = (tid & 1) * 4;
  const float* Ap = A  + (size_t)(bm * BM + lrow) * K + lk4;
  const float* Bp = Bm + (size_t)(bn * BN + lrow) * K + lk4;

  float acc[8][8];
#pragma unroll
  for (int i = 0; i < 8; i++)
#pragma unroll
    for (int j = 0; j < 8; j++) acc[i][j] = 0.0f;

  for (int k0 = 0; k0 < K; k0 += BKf) {
    const float4 av = *(const float4*)(Ap + k0);
    const float4 bv = *(const float4*)(Bp + k0);
    As[lk4 + 0][lrow] = av.x; As[lk4 + 1][lrow] = av.y;
    As[lk4 + 2][lrow] = av.z; As[lk4 + 3][lrow] = av.w;
    Bs[lk4 + 0][lrow] = bv.x; Bs[lk4 + 1][lrow] = bv.y;
    Bs[lk4 + 2][lrow] = bv.z; Bs[lk4 + 3][lrow] = bv.w;
    __syncthreads();
#pragma unroll
    for (int k = 0; k < BKf; k++) {
      const float4 alo = *(const float4*)&As[k][tm * 4];
      const float4 ahi = *(const float4*)&As[k][64 + tm * 4];
      const float4 blo = *(const float4*)&Bs[k][tn * 4];
      const float4 bhi = *(const float4*)&Bs[k][64 + tn * 4];
      const float a[8] = {alo.x, alo.y, alo.z, alo.w, ahi.x, ahi.y, ahi.z, ahi.w};
      const float b[8] = {blo.x, blo.y, blo.z, blo.w, bhi.x, bhi.y, bhi.z, bhi.w};
#pragma unroll
      for (int i = 0; i < 8; i++)
#pragma unroll
        for (int j = 0; j < 8; j++) acc[i][j] = fmaf(a[i], b[j], acc[i][j]);
    }
    __syncthreads();
  }
#pragma unroll
  for (int i = 0; i < 8; i++) {
    const int row = bm * BM + (i >> 2) * 64 + tm * 4 + (i & 3);
    float4 lo = make_float4(acc[i][0], acc[i][1], acc[i][2], acc[i][3]);
    float4 hi = make_float4(acc[i][4], acc[i][5], acc[i][6], acc[i][7]);
    *(float4*)(C + (size_t)row * N + bn * BN + tn * 4)      = lo;
    *(float4*)(C + (size_t)row * N + bn * BN + 64 + tn * 4) = hi;
  }
}

// ---------- fp32 -> bf16 conversion ------------------------------------------
__global__ __launch_bounds__(256) void cvt_bf16(const float* __restrict__ in,
                                                unsigned short* __restrict__ out, int n8) {
  const int i = blockIdx.x * 256 + threadIdx.x;
  if (i >= n8) return;
  const float4 a = ((const float4*)in)[2*i];
  const float4 b = ((const float4*)in)[2*i+1];
  u16x8 o;
  o[0]=f2bf(a.x); o[1]=f2bf(a.y); o[2]=f2bf(a.z); o[3]=f2bf(a.w);
  o[4]=f2bf(b.x); o[5]=f2bf(b.y); o[6]=f2bf(b.z); o[7]=f2bf(b.w);
  *(u16x8*)(out + 8*i) = o;
}

// ---------- bf16 MFMA NT GEMM, 128x128 tile, BK=32, double-buffered ----------
// MODE 1 (wv):   A=A0bf;              out: fp32 outf + bf16 outbf
// MODE 2 (gate): A=[A0f cvt | A1 bf]; out: sigmoid(acc+bg)*projf -> outf
// MODE 3 (q):    A=A0f (inline cvt);  out: fp32 outf
// MODE 4 (sim):  A=A0bf;              out: fp32 outf
template<int KTOT, int NOUT, int MODE>
__global__ __launch_bounds__(256) void mfma_nt(
    const unsigned short* __restrict__ A0bf,
    const float* __restrict__ A0f,
    const unsigned short* __restrict__ A1,
    const unsigned short* __restrict__ Bw,
    const float* __restrict__ bg,
    const float* __restrict__ projf,
    float* __restrict__ outf,
    unsigned short* __restrict__ outbf) {
  __shared__ __align__(16) unsigned short As[2][128 * 32];
  __shared__ __align__(16) unsigned short Bs[2][128 * 32];
  const int tid = threadIdx.x;
  const int wv = tid >> 6, l = tid & 63;
  const int bn = blockIdx.x, bm = blockIdx.y;
  const int wr = wv >> 1, wc = wv & 1;
  const int lane16 = l & 15, lhi = l >> 4;

  f32x4 acc[4][4];
#pragma unroll
  for (int mi = 0; mi < 4; mi++)
#pragma unroll
    for (int nj = 0; nj < 4; nj++)
#pragma unroll
      for (int r = 0; r < 4; r++) acc[mi][nj][r] = 0.0f;

  auto stage = [&](int buf, int t) {
    const int k0 = t * 32;
#pragma unroll
    for (int h = 0; h < 2; ++h) {
      const int p = tid + 256 * h;          // chunk index 0..511
      const int r = p >> 2, c = p & 3;
      const int q = k0 + 8 * (c ^ ((r >> 1) & 3));
      if constexpr (MODE == 3) {
        const float* asrcF = A0f + (size_t)(bm * 128 + r) * 512 + q;
        const float4 f0 = *(const float4*)asrcF;
        const float4 f1 = *(const float4*)(asrcF + 4);
        u16x8 o;
        o[0]=f2bf(f0.x); o[1]=f2bf(f0.y); o[2]=f2bf(f0.z); o[3]=f2bf(f0.w);
        o[4]=f2bf(f1.x); o[5]=f2bf(f1.y); o[6]=f2bf(f1.z); o[7]=f2bf(f1.w);
        *(u16x8*)&As[buf][(size_t)p * 8] = o;
      } else if constexpr (MODE == 2) {
        if (k0 < 512) {  // query half: fp32 load + inline cvt + ds_write
          const float* asrcF = A0f + (size_t)(bm * 128 + r) * 512 + q;
          const float4 f0 = *(const float4*)asrcF;
          const float4 f1 = *(const float4*)(asrcF + 4);
          u16x8 o;
          o[0]=f2bf(f0.x); o[1]=f2bf(f0.y); o[2]=f2bf(f0.z); o[3]=f2bf(f0.w);
          o[4]=f2bf(f1.x); o[5]=f2bf(f1.y); o[6]=f2bf(f1.z); o[7]=f2bf(f1.w);
          *(u16x8*)&As[buf][(size_t)p * 8] = o;
        } else {         // proj half: bf16 async
          const unsigned short* asrc = A1 + (size_t)(bm * 128 + r) * 512 + (q - 512);
          GLDS16(asrc, &As[buf][(4 * h + wv) * 512]);
        }
      } else {
        const unsigned short* asrc = A0bf + (size_t)(bm * 128 + r) * 512 + q;
        GLDS16(asrc, &As[buf][(4 * h + wv) * 512]);
      }
      const unsigned short* bsrc = Bw + (size_t)(bn * 128 + r) * KTOT + q;
      GLDS16(bsrc, &Bs[buf][(4 * h + wv) * 512]);
    }
  };

  auto compute = [&](int buf) {
    const int achunk = lhi ^ ((lane16 >> 1) & 3);
    bf16x8 af[4], bfr[4];
#pragma unroll
    for (int mi = 0; mi < 4; ++mi)
      af[mi] = *(const bf16x8*)&As[buf][(wr * 64 + mi * 16 + lane16) * 32 + achunk * 8];
#pragma unroll
    for (int nj = 0; nj < 4; ++nj)
      bfr[nj] = *(const bf16x8*)&Bs[buf][(wc * 64 + nj * 16 + lane16) * 32 + achunk * 8];
#pragma unroll
    for (int mi = 0; mi < 4; ++mi)
#pragma unroll
      for (int nj = 0; nj < 4; ++nj)
        acc[mi][nj] = __builtin_amdgcn_mfma_f32_16x16x32_bf16(af[mi], bfr[nj], acc[mi][nj], 0, 0, 0);
  };

  const int NT = KTOT / 32;
  stage(0, 0);
  __syncthreads();
  for (int t = 0; t < NT - 1; ++t) {
    stage((t + 1) & 1, t + 1);
    compute(t & 1);
    __syncthreads();
  }
  compute((NT - 1) & 1);

  const int rowb = bm * 128 + wr * 64 + (lhi << 2);
  const int colb = bn * 128 + wc * 64 + lane16;
#pragma unroll
  for (int mi = 0; mi < 4; ++mi) {
#pragma unroll
    for (int nj = 0; nj < 4; ++nj) {
      const int col = colb + nj * 16;
#pragma unroll
      for (int r = 0; r < 4; ++r) {
        const int row = rowb + mi * 16 + r;
        const size_t o = (size_t)row * NOUT + col;
        const float v = acc[mi][nj][r];
        if constexpr (MODE == 2) {
          const float x = v + bg[col];
          const float g = 1.0f / (1.0f + __expf(-x));
          outf[o] = g * projf[o];
        } else if constexpr (MODE == 1) {
          outf[o]  = v;
          outbf[o] = f2bf(v);
        } else {
          outf[o] = v;
        }
      }
    }
  }
}

// ---------- wave-per-row: coarse top-4 + margin + K'-rescore + gather --------
// Lane l holds sim[16l..16l+16) fp32 and query[8l..8l+8).
// Rescore r(idx) = dot(query_row, Kp[idx]) == q . kn[idx]  (fp32-exact class).
__global__ __launch_bounds__(256) void topk_rescore_gather(
    const float* __restrict__ simf,
    const float* __restrict__ query,
    const float* __restrict__ invq,
    const float* __restrict__ Kp,
    const float* __restrict__ vals,
    unsigned short* __restrict__ retr) {
  const int w = threadIdx.x >> 6, l = threadIdx.x & 63;
  const int b = blockIdx.x * 4 + w;
  const float NEG = -3.402823466e38f;

  // sim row: 16 fp32 per lane
  const float4* sp = (const float4*)(simf + (size_t)b * E_ + 16 * l);
  const float4 s0 = sp[0], s1 = sp[1], s2 = sp[2], s3 = sp[3];
  float v[16];
  v[0]=s0.x; v[1]=s0.y; v[2]=s0.z; v[3]=s0.w;
  v[4]=s1.x; v[5]=s1.y; v[6]=s1.z; v[7]=s1.w;
  v[8]=s2.x; v[9]=s2.y; v[10]=s2.z; v[11]=s2.w;
  v[12]=s3.x; v[13]=s3.y; v[14]=s3.z; v[15]=s3.w;

  // query row: 8 floats per lane
  const float4* qp = (const float4*)(query + (size_t)b * D_ + 8 * l);
  const float4 q0 = qp[0], q1 = qp[1];

  // fp32 rescore via K': all 64 lanes cooperate, result in all lanes
  auto score = [&](int idx) -> float {
    const float4* kp = (const float4*)(Kp + (size_t)idx * D_ + 8 * l);
    const float4 k0 = kp[0], k1 = kp[1];
    float p = q0.x * k0.x;
    p = fmaf(q0.y, k0.y, p); p = fmaf(q0.z, k0.z, p); p = fmaf(q0.w, k0.w, p);
    p = fmaf(q1.x, k1.x, p); p = fmaf(q1.y, k1.y, p);
    p = fmaf(q1.z, k1.z, p); p = fmaf(q1.w, k1.w, p);
#pragma unroll
    for (int off = 32; off > 0; off >>= 1) p += __shfl_xor(p, off, 64);
    return p;
  };

  // exact top-4 sorted regs, comparator (v desc, i asc)
  float rv0 = NEG, rv1 = NEG, rv2 = NEG, rv3 = NEG;
  int   ri0 = 0x7fffffff, ri1 = 0x7fffffff, ri2 = 0x7fffffff, ri3 = 0x7fffffff;
  auto ins = [&](float nv, int ni) {
    if (nv > rv0 || (nv == rv0 && ni < ri0)) {
      rv3 = rv2; ri3 = ri2; rv2 = rv1; ri2 = ri1; rv1 = rv0; ri1 = ri0; rv0 = nv; ri0 = ni;
    } else if (nv > rv1 || (nv == rv1 && ni < ri1)) {
      rv3 = rv2; ri3 = ri2; rv2 = rv1; ri2 = ri1; rv1 = nv; ri1 = ni;
    } else if (nv > rv2 || (nv == rv2 && ni < ri2)) {
      rv3 = rv2; ri3 = ri2; rv2 = nv; ri2 = ni;
    } else if (nv > rv3 || (nv == rv3 && ni < ri3)) {
      rv3 = nv; ri3 = ni;
    }
  };

  // 4 coarse argmax passes (kill via bitmask)
  unsigned killed = 0;
  float t4 = NEG;
#pragma unroll
  for (int k = 0; k < 4; k++) {
    float bv = NEG; int bs = 0;
#pragma unroll
    for (int j = 0; j < 16; j++) {
      const float vj = ((killed >> j) & 1u) ? NEG : v[j];
      if (vj > bv) { bv = vj; bs = j; }
    }
    int bi = l * 16 + bs;
#pragma unroll
    for (int off = 32; off > 0; off >>= 1) {
      const float ov = __shfl_xor(bv, off, 64);
      const int   oi = __shfl_xor(bi, off, 64);
      if (ov > bv || (ov == bv && oi < bi)) { bv = ov; bi = oi; }
    }
    if ((bi >> 4) == l) killed |= 1u << (bi & 15);
    ins(score(bi), bi);
    t4 = bv;  // after last pass: coarse 4th value
  }

  // margin candidates: uniform ballot + ctz walk
  const float thr = t4 - 0.006f;
#pragma unroll
  for (int s = 0; s < 16; s++) {
    const bool pred = (((killed >> s) & 1u) == 0u) && (v[s] >= thr);
    unsigned long long m = __ballot(pred);
    while (m) {
      const int ln = __builtin_ctzll(m);
      m &= m - 1;
      const int idx = ln * 16 + s;
      ins(score(idx), idx);
    }
  }

  // normalize (positive scale: ranking unchanged), softmax
  const float iq = invq[b];
  const float f0 = rv0 * iq, f1 = rv1 * iq, f2 = rv2 * iq, f3 = rv3 * iq;
  const float mx = 5.0f * f0;
  const float e0 = expf(5.0f * f0 - mx), e1 = expf(5.0f * f1 - mx);
  const float e2 = expf(5.0f * f2 - mx), e3 = expf(5.0f * f3 - mx);
  const float wi = 1.0f / (e0 + e1 + e2 + e3);
  const float w0 = e0 * wi, w1 = e1 * wi, w2 = e2 * wi, w3 = e3 * wi;

  // gather: 8 cols per lane, vals L2-resident
  const float4* v0p = (const float4*)(vals + (size_t)ri0 * D_ + 8 * l);
  const float4* v1p = (const float4*)(vals + (size_t)ri1 * D_ + 8 * l);
  const float4* v2p = (const float4*)(vals + (size_t)ri2 * D_ + 8 * l);
  const float4* v3p = (const float4*)(vals + (size_t)ri3 * D_ + 8 * l);
  const float4 a0 = v0p[0], b0 = v0p[1];
  const float4 a1 = v1p[0], b1 = v1p[1];
  const float4 a2 = v2p[0], b2 = v2p[1];
  const float4 a3 = v3p[0], b3 = v3p[1];
  u16x8 o;
  o[0] = f2bf(w0 * a0.x + w1 * a1.x + w2 * a2.x + w3 * a3.x);
  o[1] = f2bf(w0 * a0.y + w1 * a1.y + w2 * a2.y + w3 * a3.y);
  o[2] = f2bf(w0 * a0.z + w1 * a1.z + w2 * a2.z + w3 * a3.z);
  o[3] = f2bf(w0 * a0.w + w1 * a1.w + w2 * a2.w + w3 * a3.w);
  o[4] = f2bf(w0 * b0.x + w1 * b1.x + w2 * b2.x + w3 * b3.x);
  o[5] = f2bf(w0 * b0.y + w1 * b1.y + w2 * b2.y + w3 * b3.y);
  o[6] = f2bf(w0 * b0.z + w1 * b1.z + w2 * b2.z + w3 * b3.z);
  o[7] = f2bf(w0 * b0.w + w1 * b1.w + w2 * b2.w + w3 * b3.w);
  *(u16x8*)(retr + (size_t)b * D_ + 8 * l) = o;
}

extern "C" void kernel_launch(void* const* d_in, const int* in_sizes, int n_in,
                              void* d_out, int out_size, void* d_ws, size_t ws_size,
                              hipStream_t stream) {
  (void)in_sizes; (void)n_in; (void)out_size; (void)ws_size;
  const float* query = (const float*)d_in[0];
  const float* keys  = (const float*)d_in[1];
  const float* vals  = (const float*)d_in[2];
  const float* Wq    = (const float*)d_in[3];
  const float* Wv    = (const float*)d_in[4];
  const float* Wg    = (const float*)d_in[5];
  const float* bg    = (const float*)d_in[6];
  float* out = (float*)d_out;

  char* ws = (char*)d_ws;
  const size_t M = 1u << 20;
  float*          simf    = (float*)(ws);                   // [0,64M)
  float*          qF32    = (float*)(ws + 32*M);            // dead before sim GEMM
  float*          projF   = (float*)(ws);                   // [0,32M) after topk
  unsigned short* proj_bf = (unsigned short*)(ws + 32*M);   // [32M,48M) after topk
  unsigned short* qn_bf   = (unsigned short*)(ws + 64*M);   // [64M,80M)
  unsigned short* retr_bf = (unsigned short*)(ws + 64*M);   // overlay after sim
  unsigned short* kn_bf   = (unsigned short*)(ws + 80*M);   // 1 MB
  float*          keysN   = (float*)(ws + 81*M);            // 2 MB
  float*          WqT     = (float*)(ws + 83*M);            // 1 MB
  float*          Kp      = (float*)(ws + 84*M);            // 2 MB
  unsigned short* Wq_bf   = (unsigned short*)(ws + 86*M);   // 0.5 MB
  unsigned short* Wv_bf   = (unsigned short*)(ws + 86*M + 512*1024u);
  unsigned short* Wg_bf   = (unsigned short*)(ws + 87*M);   // 1 MB
  float*          invq    = (float*)(ws + 88*M);            // 64 KB

  l2norm_keys<<<E_, 64, 0, stream>>>(keys, keysN, kn_bf);
  transpose512<<<dim3(16, 16), 256, 0, stream>>>(Wq, WqT);
  cvt_bf16<<<(D_ * D_ / 8 + 255) / 256, 256, 0, stream>>>(Wq, Wq_bf, D_ * D_ / 8);
  cvt_bf16<<<(D_ * D_ / 8 + 255) / 256, 256, 0, stream>>>(Wv, Wv_bf, D_ * D_ / 8);
  cvt_bf16<<<(D_ * 2 * D_ / 8 + 255) / 256, 256, 0, stream>>>(Wg, Wg_bf, D_ * 2 * D_ / 8);

  // K' = keysN @ Wq  (fp32 exact-class; rescore basis)
  sgemm_v2<<<dim3(D_ / BN, E_ / BM), 256, 0, stream>>>(keysN, WqT, Kp, E_, D_, D_);

  // q (bf16 MFMA; only feeds coarse sim + |q|)
  mfma_nt<512, 512, 3><<<dim3(D_ / 128, B_ / 128), 256, 0, stream>>>(
      nullptr, query, nullptr, Wq_bf, nullptr, nullptr, qF32, nullptr);
  l2norm_q<<<B_, 64, 0, stream>>>(qF32, qn_bf, invq);

  // coarse sim fp32: [B,E]
  mfma_nt<512, 1024, 4><<<dim3(E_ / 128, B_ / 128), 256, 0, stream>>>(
      qn_bf, nullptr, nullptr, kn_bf, nullptr, nullptr, simf, nullptr);

  topk_rescore_gather<<<B_ / 4, 256, 0, stream>>>(simf, query, invq, Kp, vals, retr_bf);

  // proj = retrieved @ Wv^T  (fp32 + bf16 outputs)
  mfma_nt<512, 512, 1><<<dim3(D_ / 128, B_ / 128), 256, 0, stream>>>(
      retr_bf, nullptr, nullptr, Wv_bf, nullptr, nullptr, projF, proj_bf);

  // out = sigmoid([query|proj] @ Wg^T + bg) * proj
  mfma_nt<1024, 512, 2><<<dim3(D_ / 128, B_ / 128), 256, 0, stream>>>(
      nullptr, query, proj_bf, Wg_bf, bg, projF, out, nullptr);
}

// Round 6
// 235.389 us; speedup vs baseline: 3.9804x; 1.2667x over previous
//
#include <hip/hip_runtime.h>
#include <hip/hip_bf16.h>
#include <math.h>

// EpisodicMemory round 6.
// - qgemm_norm: fused bf16-MFMA q GEMM + row L2-norm -> qn_bf + invq (no qF32)
// - sim MFMA -> bf16 store (margin 0.008 covers), topk reads 32MB not 64MB
// - topk: pooled block-cooperative fp32 rescore via Kp (= keysN @ Wq, fp32)
// - Kp GEMM: 64x64 tiles -> 128 blocks (was 32)
// ws layout (<=98 MB):
//   [0,32M)   sim_bf (sim->topk)     -> projF overlay (Wv->gate)
//   [32M,48M) qn_bf (q->sim)         -> retr_bf overlay (topk->Wv)
//   [48M,64M) proj_bf (Wv->gate)
//   [64M,66M) keysN  [66M,67M) kn_bf  [67M,68M) WqT  [68M,70M) Kp
//   [70M,70.5M) Wq_bf [70.5M,71M) Wv_bf [71M,72M) Wg_bf [72M,+64K) invq

#define B_ 16384
#define D_ 512
#define E_ 1024

typedef __attribute__((ext_vector_type(8))) short bf16x8;
typedef __attribute__((ext_vector_type(4))) float f32x4;
typedef __attribute__((ext_vector_type(8))) unsigned short u16x8;

__device__ __forceinline__ unsigned short f2bf(float f) {
  unsigned u = __builtin_bit_cast(unsigned, f);
  unsigned r = (u + 0x7fffu + ((u >> 16) & 1u)) >> 16;
  return (unsigned short)r;
}
__device__ __forceinline__ float bf2f(unsigned short u) {
  return __builtin_bit_cast(float, (unsigned)u << 16);
}

#define GLDS16(g, l)                                                          \
  __builtin_amdgcn_global_load_lds(                                           \
      (const __attribute__((address_space(1))) void*)(g),                     \
      (__attribute__((address_space(3))) void*)(l), 16, 0, 0)

// ---------- L2 normalize keys: fp32 out + bf16 out ---------------------------
__global__ __launch_bounds__(64) void l2norm_keys(const float* __restrict__ in,
                                                  float* __restrict__ outF,
                                                  unsigned short* __restrict__ outBF) {
  const int row  = blockIdx.x;
  const int lane = threadIdx.x;
  const float4* p4 = (const float4*)(in + (size_t)row * D_);
  float4 a = p4[lane];
  float4 b = p4[lane + 64];
  float ss = a.x*a.x + a.y*a.y + a.z*a.z + a.w*a.w
           + b.x*b.x + b.y*b.y + b.z*b.z + b.w*b.w;
#pragma unroll
  for (int off = 32; off > 0; off >>= 1) ss += __shfl_xor(ss, off, 64);
  const float inv = 1.0f / fmaxf(sqrtf(ss), 1e-12f);
  a.x *= inv; a.y *= inv; a.z *= inv; a.w *= inv;
  b.x *= inv; b.y *= inv; b.z *= inv; b.w *= inv;
  float4* o4 = (float4*)(outF + (size_t)row * D_);
  o4[lane]      = a;
  o4[lane + 64] = b;
  ushort4 ua, ub;
  ua.x=f2bf(a.x); ua.y=f2bf(a.y); ua.z=f2bf(a.z); ua.w=f2bf(a.w);
  ub.x=f2bf(b.x); ub.y=f2bf(b.y); ub.z=f2bf(b.z); ub.w=f2bf(b.w);
  *(ushort4*)(outBF + (size_t)row * D_ + 4*lane)       = ua;
  *(ushort4*)(outBF + (size_t)row * D_ + 256 + 4*lane) = ub;
}

// ---------- 512x512 fp32 transpose (for WqT) ---------------------------------
__global__ __launch_bounds__(256) void transpose512(const float* __restrict__ in,
                                                    float* __restrict__ out) {
  __shared__ float t[32][33];
  const int tx = threadIdx.x & 31, ty = threadIdx.x >> 5;
  const int bx = blockIdx.x, by = blockIdx.y;
#pragma unroll
  for (int k = 0; k < 4; k++)
    t[ty + 8*k][tx] = in[(size_t)(by*32 + ty + 8*k) * 512 + bx*32 + tx];
  __syncthreads();
#pragma unroll
  for (int k = 0; k < 4; k++)
    out[(size_t)(bx*32 + ty + 8*k) * 512 + by*32 + tx] = t[tx][ty + 8*k];
}

// ---------- fp32 NT SGEMM 64x64 tiles (Kp = keysN @ Wq, via WqT) -------------
// C[1024,512] = A[1024,512] * Bm[512,512]^T. Grid (8, 16) = 128 blocks.
__global__ __launch_bounds__(256) void sgemm64(const float* __restrict__ A,
                                               const float* __restrict__ Bm,
                                               float* __restrict__ C) {
  __shared__ float As[16][64];
  __shared__ float Bs[16][64];
  const int tid = threadIdx.x;
  const int bn = blockIdx.x, bm = blockIdx.y;
  const int tm = tid >> 4, tn = tid & 15;
  const int r = tid >> 2, k4 = (tid & 3) * 4;
  const float* Ap = A  + (size_t)(bm*64 + r) * 512 + k4;
  const float* Bp = Bm + (size_t)(bn*64 + r) * 512 + k4;
  float acc[4][4];
#pragma unroll
  for (int i = 0; i < 4; i++)
#pragma unroll
    for (int j = 0; j < 4; j++) acc[i][j] = 0.0f;

  for (int k0 = 0; k0 < 512; k0 += 16) {
    const float4 av = *(const float4*)(Ap + k0);
    const float4 bv = *(const float4*)(Bp + k0);
    As[k4+0][r]=av.x; As[k4+1][r]=av.y; As[k4+2][r]=av.z; As[k4+3][r]=av.w;
    Bs[k4+0][r]=bv.x; Bs[k4+1][r]=bv.y; Bs[k4+2][r]=bv.z; Bs[k4+3][r]=bv.w;
    __syncthreads();
#pragma unroll
    for (int k = 0; k < 16; k++) {
      const float4 a = *(const float4*)&As[k][tm*4];
      const float4 b = *(const float4*)&Bs[k][tn*4];
      const float aa[4] = {a.x,a.y,a.z,a.w}, bb[4] = {b.x,b.y,b.z,b.w};
#pragma unroll
      for (int i = 0; i < 4; i++)
#pragma unroll
        for (int j = 0; j < 4; j++) acc[i][j] = fmaf(aa[i], bb[j], acc[i][j]);
    }
    __syncthreads();
  }
#pragma unroll
  for (int i = 0; i < 4; i++) {
    float4 o = make_float4(acc[i][0], acc[i][1], acc[i][2], acc[i][3]);
    *(float4*)(C + (size_t)(bm*64 + tm*4 + i) * 512 + bn*64 + tn*4) = o;
  }
}

// ---------- fp32 -> bf16 conversion ------------------------------------------
__global__ __launch_bounds__(256) void cvt_bf16(const float* __restrict__ in,
                                                unsigned short* __restrict__ out, int n8) {
  const int i = blockIdx.x * 256 + threadIdx.x;
  if (i >= n8) return;
  const float4 a = ((const float4*)in)[2*i];
  const float4 b = ((const float4*)in)[2*i+1];
  u16x8 o;
  o[0]=f2bf(a.x); o[1]=f2bf(a.y); o[2]=f2bf(a.z); o[3]=f2bf(a.w);
  o[4]=f2bf(b.x); o[5]=f2bf(b.y); o[6]=f2bf(b.z); o[7]=f2bf(b.w);
  *(u16x8*)(out + 8*i) = o;
}

// ---------- fused q GEMM + row L2 norm ---------------------------------------
// Per block: 64 query rows x all 512 cols (4 waves x 128 cols). K=512, BK=32.
// Epilogue: row sumsq (lane16 butterfly + cross-wave LDS), write qn_bf + invq.
__global__ __launch_bounds__(256) void qgemm_norm(
    const float* __restrict__ query,
    const unsigned short* __restrict__ Wqbf,
    unsigned short* __restrict__ qnbf,
    float* __restrict__ invq) {
  __shared__ __align__(16) unsigned short As[2][64 * 32];
  __shared__ __align__(16) unsigned short Bs[2][512 * 32];
  __shared__ float rowss[4][64];
  const int tid = threadIdx.x;
  const int wv = tid >> 6, l = tid & 63;
  const int m0 = blockIdx.x * 64;
  const int lane16 = l & 15, lhi = l >> 4;

  f32x4 acc[4][8];
#pragma unroll
  for (int mi = 0; mi < 4; mi++)
#pragma unroll
    for (int nj = 0; nj < 8; nj++)
#pragma unroll
      for (int r = 0; r < 4; r++) acc[mi][nj][r] = 0.0f;

  auto stage = [&](int buf, int t) {
    const int k0 = t * 32;
    {  // A: 64 rows x 4 chunks = 256 = one chunk per thread (fp32 cvt inline)
      const int p = tid;
      const int r = p >> 2, c = p & 3;
      const int q = k0 + 8 * (c ^ ((r >> 1) & 3));
      const float* src = query + (size_t)(m0 + r) * 512 + q;
      const float4 f0 = *(const float4*)src;
      const float4 f1 = *(const float4*)(src + 4);
      u16x8 o;
      o[0]=f2bf(f0.x); o[1]=f2bf(f0.y); o[2]=f2bf(f0.z); o[3]=f2bf(f0.w);
      o[4]=f2bf(f1.x); o[5]=f2bf(f1.y); o[6]=f2bf(f1.z); o[7]=f2bf(f1.w);
      *(u16x8*)&As[buf][p * 8] = o;
    }
#pragma unroll
    for (int h = 0; h < 8; ++h) {  // B: 512 rows x 4 chunks via global_load_lds
      const int p = tid + 256 * h;
      const int r = p >> 2, c = p & 3;
      const int q = k0 + 8 * (c ^ ((r >> 1) & 3));
      GLDS16(Wqbf + (size_t)r * 512 + q, &Bs[buf][(4 * h + wv) * 512]);
    }
  };
  auto compute = [&](int buf) {
    const int achunk = lhi ^ ((lane16 >> 1) & 3);
    bf16x8 af[4], bfr[8];
#pragma unroll
    for (int mi = 0; mi < 4; ++mi)
      af[mi] = *(const bf16x8*)&As[buf][(mi * 16 + lane16) * 32 + achunk * 8];
#pragma unroll
    for (int nj = 0; nj < 8; ++nj)
      bfr[nj] = *(const bf16x8*)&Bs[buf][(wv * 128 + nj * 16 + lane16) * 32 + achunk * 8];
#pragma unroll
    for (int mi = 0; mi < 4; ++mi)
#pragma unroll
      for (int nj = 0; nj < 8; ++nj)
        acc[mi][nj] = __builtin_amdgcn_mfma_f32_16x16x32_bf16(af[mi], bfr[nj], acc[mi][nj], 0, 0, 0);
  };

  stage(0, 0);
  __syncthreads();
  for (int t = 0; t < 15; ++t) {
    stage((t + 1) & 1, t + 1);
    compute(t & 1);
    __syncthreads();
  }
  compute(1);

  // row sum-of-squares: per-lane over its 8 cols, butterfly over lane16 bits
  float ss[4][4];
#pragma unroll
  for (int mi = 0; mi < 4; mi++)
#pragma unroll
    for (int r = 0; r < 4; r++) ss[mi][r] = 0.0f;
#pragma unroll
  for (int mi = 0; mi < 4; mi++)
#pragma unroll
    for (int nj = 0; nj < 8; nj++)
#pragma unroll
      for (int r = 0; r < 4; r++) {
        const float x = acc[mi][nj][r];
        ss[mi][r] = fmaf(x, x, ss[mi][r]);
      }
#pragma unroll
  for (int off = 1; off < 16; off <<= 1)
#pragma unroll
    for (int mi = 0; mi < 4; mi++)
#pragma unroll
      for (int r = 0; r < 4; r++) ss[mi][r] += __shfl_xor(ss[mi][r], off, 64);
  if (lane16 == 0) {
#pragma unroll
    for (int mi = 0; mi < 4; mi++)
#pragma unroll
      for (int r = 0; r < 4; r++) rowss[wv][mi * 16 + lhi * 4 + r] = ss[mi][r];
  }
  __syncthreads();

#pragma unroll
  for (int mi = 0; mi < 4; mi++) {
#pragma unroll
    for (int r = 0; r < 4; r++) {
      const int row = mi * 16 + lhi * 4 + r;
      const float tot = rowss[0][row] + rowss[1][row] + rowss[2][row] + rowss[3][row];
      const float inv = 1.0f / fmaxf(sqrtf(tot), 1e-12f);
      if (wv == 0 && lane16 == 0) invq[m0 + row] = inv;
#pragma unroll
      for (int nj = 0; nj < 8; nj++)
        qnbf[(size_t)(m0 + row) * 512 + wv * 128 + nj * 16 + lane16] =
            f2bf(acc[mi][nj][r] * inv);
    }
  }
}

// ---------- bf16 MFMA NT GEMM, 128x128 tile, BK=32, double-buffered ----------
// MODE 0 (sim):  A=A0bf; out: bf16 outbf
// MODE 1 (wv):   A=A0bf; out: fp32 outf + bf16 outbf
// MODE 2 (gate): A=[A0f cvt | A1 bf]; out: sigmoid(acc+bg)*projf -> outf
template<int KTOT, int NOUT, int MODE>
__global__ __launch_bounds__(256) void mfma_nt(
    const unsigned short* __restrict__ A0bf,
    const float* __restrict__ A0f,
    const unsigned short* __restrict__ A1,
    const unsigned short* __restrict__ Bw,
    const float* __restrict__ bg,
    const float* __restrict__ projf,
    float* __restrict__ outf,
    unsigned short* __restrict__ outbf) {
  __shared__ __align__(16) unsigned short As[2][128 * 32];
  __shared__ __align__(16) unsigned short Bs[2][128 * 32];
  const int tid = threadIdx.x;
  const int wv = tid >> 6, l = tid & 63;
  const int bn = blockIdx.x, bm = blockIdx.y;
  const int wr = wv >> 1, wc = wv & 1;
  const int lane16 = l & 15, lhi = l >> 4;

  f32x4 acc[4][4];
#pragma unroll
  for (int mi = 0; mi < 4; mi++)
#pragma unroll
    for (int nj = 0; nj < 4; nj++)
#pragma unroll
      for (int r = 0; r < 4; r++) acc[mi][nj][r] = 0.0f;

  auto stage = [&](int buf, int t) {
    const int k0 = t * 32;
#pragma unroll
    for (int h = 0; h < 2; ++h) {
      const int p = tid + 256 * h;
      const int r = p >> 2, c = p & 3;
      const int q = k0 + 8 * (c ^ ((r >> 1) & 3));
      if constexpr (MODE == 2) {
        if (k0 < 512) {
          const float* asrcF = A0f + (size_t)(bm * 128 + r) * 512 + q;
          const float4 f0 = *(const float4*)asrcF;
          const float4 f1 = *(const float4*)(asrcF + 4);
          u16x8 o;
          o[0]=f2bf(f0.x); o[1]=f2bf(f0.y); o[2]=f2bf(f0.z); o[3]=f2bf(f0.w);
          o[4]=f2bf(f1.x); o[5]=f2bf(f1.y); o[6]=f2bf(f1.z); o[7]=f2bf(f1.w);
          *(u16x8*)&As[buf][(size_t)p * 8] = o;
        } else {
          const unsigned short* asrc = A1 + (size_t)(bm * 128 + r) * 512 + (q - 512);
          GLDS16(asrc, &As[buf][(4 * h + wv) * 512]);
        }
      } else {
        const unsigned short* asrc = A0bf + (size_t)(bm * 128 + r) * 512 + q;
        GLDS16(asrc, &As[buf][(4 * h + wv) * 512]);
      }
      const unsigned short* bsrc = Bw + (size_t)(bn * 128 + r) * KTOT + q;
      GLDS16(bsrc, &Bs[buf][(4 * h + wv) * 512]);
    }
  };

  auto compute = [&](int buf) {
    const int achunk = lhi ^ ((lane16 >> 1) & 3);
    bf16x8 af[4], bfr[4];
#pragma unroll
    for (int mi = 0; mi < 4; ++mi)
      af[mi] = *(const bf16x8*)&As[buf][(wr * 64 + mi * 16 + lane16) * 32 + achunk * 8];
#pragma unroll
    for (int nj = 0; nj < 4; ++nj)
      bfr[nj] = *(const bf16x8*)&Bs[buf][(wc * 64 + nj * 16 + lane16) * 32 + achunk * 8];
#pragma unroll
    for (int mi = 0; mi < 4; ++mi)
#pragma unroll
      for (int nj = 0; nj < 4; ++nj)
        acc[mi][nj] = __builtin_amdgcn_mfma_f32_16x16x32_bf16(af[mi], bfr[nj], acc[mi][nj], 0, 0, 0);
  };

  const int NT = KTOT / 32;
  stage(0, 0);
  __syncthreads();
  for (int t = 0; t < NT - 1; ++t) {
    stage((t + 1) & 1, t + 1);
    compute(t & 1);
    __syncthreads();
  }
  compute((NT - 1) & 1);

  const int rowb = bm * 128 + wr * 64 + (lhi << 2);
  const int colb = bn * 128 + wc * 64 + lane16;
#pragma unroll
  for (int mi = 0; mi < 4; ++mi) {
#pragma unroll
    for (int nj = 0; nj < 4; ++nj) {
      const int col = colb + nj * 16;
#pragma unroll
      for (int r = 0; r < 4; ++r) {
        const int row = rowb + mi * 16 + r;
        const size_t o = (size_t)row * NOUT + col;
        const float v = acc[mi][nj][r];
        if constexpr (MODE == 2) {
          const float x = v + bg[col];
          const float g = 1.0f / (1.0f + __expf(-x));
          outf[o] = g * projf[o];
        } else if constexpr (MODE == 1) {
          outf[o]  = v;
          outbf[o] = f2bf(v);
        } else {
          outbf[o] = f2bf(v);
        }
      }
    }
  }
}

// ---------- topk v3: coarse top-4 + margin -> pooled fp32 rescore -> gather --
// 4 waves = 4 rows per block. Candidates pooled in LDS, rescored in parallel
// across all 4 waves (independent iterations), then per-row exact top-4 with
// (value desc, index asc), softmax, weighted gather of values.
__global__ __launch_bounds__(256) void topk_rescore_gather(
    const unsigned short* __restrict__ simbf,
    const float* __restrict__ query,
    const float* __restrict__ invq,
    const float* __restrict__ Kp,
    const float* __restrict__ vals,
    unsigned short* __restrict__ retr) {
  const int w = threadIdx.x >> 6, l = threadIdx.x & 63;
  const int b = blockIdx.x * 4 + w;
  const float NEG = -3.402823466e38f;
  __shared__ float qT[4][512];   // lane-major: qT[r][j*64+l] = query[r][8l+j]
  __shared__ int   s_idx[4][16];
  __shared__ int   s_cnt[4];
  __shared__ int   s_fr[64];
  __shared__ int   s_fi[64];
  __shared__ float s_fs[64];

  // stage query row (transposed -> conflict-free LDS reads in rescore)
  const float4* qp = (const float4*)(query + (size_t)b * D_ + 8 * l);
  const float4 qa = qp[0], qb = qp[1];
  qT[w][0*64+l]=qa.x; qT[w][1*64+l]=qa.y; qT[w][2*64+l]=qa.z; qT[w][3*64+l]=qa.w;
  qT[w][4*64+l]=qb.x; qT[w][5*64+l]=qb.y; qT[w][6*64+l]=qb.z; qT[w][7*64+l]=qb.w;

  // sim row: 16 bf16 per lane
  const u16x8* sp = (const u16x8*)(simbf + (size_t)b * E_ + 16 * l);
  const u16x8 s0 = sp[0], s1 = sp[1];
  float v[16];
#pragma unroll
  for (int j = 0; j < 8; j++) {
    v[j]     = bf2f((unsigned short)s0[j]);
    v[8 + j] = bf2f((unsigned short)s1[j]);
  }

  // 4 coarse argmax passes (collect only)
  unsigned killed = 0;
  float t4 = NEG;
  int c0 = 0, c1 = 0, c2 = 0, c3 = 0;
#pragma unroll
  for (int k = 0; k < 4; k++) {
    float bv = NEG; int bs = 0;
#pragma unroll
    for (int j = 0; j < 16; j++) {
      const float vj = ((killed >> j) & 1u) ? NEG : v[j];
      if (vj > bv) { bv = vj; bs = j; }
    }
    int bi = l * 16 + bs;
#pragma unroll
    for (int off = 32; off > 0; off >>= 1) {
      const float ov = __shfl_xor(bv, off, 64);
      const int   oi = __shfl_xor(bi, off, 64);
      if (ov > bv || (ov == bv && oi < bi)) { bv = ov; bi = oi; }
    }
    if ((bi >> 4) == l) killed |= 1u << (bi & 15);
    if (k == 0) c0 = bi; else if (k == 1) c1 = bi; else if (k == 2) c2 = bi; else c3 = bi;
    t4 = bv;
  }
  if (l == 0) { s_idx[w][0]=c0; s_idx[w][1]=c1; s_idx[w][2]=c2; s_idx[w][3]=c3; }

  // margin candidates (uniform ballot walk)
  int cnt = 4;
  const float thr = t4 - 0.008f;
#pragma unroll
  for (int s = 0; s < 16; s++) {
    const bool pred = (((killed >> s) & 1u) == 0u) && (v[s] >= thr);
    unsigned long long m = __ballot(pred);
    while (m) {
      const int ln = __builtin_ctzll(m);
      m &= m - 1;
      if (cnt < 16) { if (l == 0) s_idx[w][cnt] = ln * 16 + s; }
      cnt++;
    }
  }
  if (cnt > 16) cnt = 16;
  if (l == 0) s_cnt[w] = cnt;
  __syncthreads();

  // flatten candidate lists
  const int n0 = s_cnt[0], n1 = s_cnt[1], n2 = s_cnt[2], n3 = s_cnt[3];
  const int tot = n0 + n1 + n2 + n3;
  const int off = (w > 0 ? n0 : 0) + (w > 1 ? n1 : 0) + (w > 2 ? n2 : 0);
  if (l < s_cnt[w]) { s_fr[off + l] = w; s_fi[off + l] = s_idx[w][l]; }
  __syncthreads();

  // pooled rescore: each wave takes every 4th candidate (any row)
  for (int g = w; g < tot; g += 4) {
    const int r   = s_fr[g];
    const int idx = s_fi[g];
    const float4* kp = (const float4*)(Kp + (size_t)idx * D_ + 8 * l);
    const float4 k0 = kp[0], k1 = kp[1];
    float p =        qT[r][0*64+l] * k0.x;
    p = fmaf(qT[r][1*64+l], k0.y, p);
    p = fmaf(qT[r][2*64+l], k0.z, p);
    p = fmaf(qT[r][3*64+l], k0.w, p);
    p = fmaf(qT[r][4*64+l], k1.x, p);
    p = fmaf(qT[r][5*64+l], k1.y, p);
    p = fmaf(qT[r][6*64+l], k1.z, p);
    p = fmaf(qT[r][7*64+l], k1.w, p);
#pragma unroll
    for (int o = 32; o > 0; o >>= 1) p += __shfl_xor(p, o, 64);
    if (l == 0) s_fs[g] = p;
  }
  __syncthreads();

  // per-row exact top-4 (value desc, index asc)
  float rv0 = NEG, rv1 = NEG, rv2 = NEG, rv3 = NEG;
  int   ri0 = 0x7fffffff, ri1 = 0x7fffffff, ri2 = 0x7fffffff, ri3 = 0x7fffffff;
  auto ins = [&](float nv, int ni) {
    if (nv > rv0 || (nv == rv0 && ni < ri0)) {
      rv3 = rv2; ri3 = ri2; rv2 = rv1; ri2 = ri1; rv1 = rv0; ri1 = ri0; rv0 = nv; ri0 = ni;
    } else if (nv > rv1 || (nv == rv1 && ni < ri1)) {
      rv3 = rv2; ri3 = ri2; rv2 = rv1; ri2 = ri1; rv1 = nv; ri1 = ni;
    } else if (nv > rv2 || (nv == rv2 && ni < ri2)) {
      rv3 = rv2; ri3 = ri2; rv2 = nv; ri2 = ni;
    } else if (nv > rv3 || (nv == rv3 && ni < ri3)) {
      rv3 = nv; ri3 = ni;
    }
  };
  const int mycnt = s_cnt[w];
  for (int j = 0; j < mycnt; j++) ins(s_fs[off + j], s_fi[off + j]);

  // softmax (positive scale invq preserves ranking)
  const float iq = invq[b];
  const float f0 = rv0 * iq, f1 = rv1 * iq, f2 = rv2 * iq, f3 = rv3 * iq;
  const float mx = 5.0f * f0;
  const float e0 = expf(5.0f * f0 - mx), e1 = expf(5.0f * f1 - mx);
  const float e2 = expf(5.0f * f2 - mx), e3 = expf(5.0f * f3 - mx);
  const float wi = 1.0f / (e0 + e1 + e2 + e3);
  const float w0 = e0 * wi, w1 = e1 * wi, w2 = e2 * wi, w3 = e3 * wi;

  // gather
  const float4* v0p = (const float4*)(vals + (size_t)ri0 * D_ + 8 * l);
  const float4* v1p = (const float4*)(vals + (size_t)ri1 * D_ + 8 * l);
  const float4* v2p = (const float4*)(vals + (size_t)ri2 * D_ + 8 * l);
  const float4* v3p = (const float4*)(vals + (size_t)ri3 * D_ + 8 * l);
  const float4 a0 = v0p[0], b0 = v0p[1];
  const float4 a1 = v1p[0], b1 = v1p[1];
  const float4 a2 = v2p[0], b2 = v2p[1];
  const float4 a3 = v3p[0], b3 = v3p[1];
  u16x8 o;
  o[0] = f2bf(w0 * a0.x + w1 * a1.x + w2 * a2.x + w3 * a3.x);
  o[1] = f2bf(w0 * a0.y + w1 * a1.y + w2 * a2.y + w3 * a3.y);
  o[2] = f2bf(w0 * a0.z + w1 * a1.z + w2 * a2.z + w3 * a3.z);
  o[3] = f2bf(w0 * a0.w + w1 * a1.w + w2 * a2.w + w3 * a3.w);
  o[4] = f2bf(w0 * b0.x + w1 * b1.x + w2 * b2.x + w3 * b3.x);
  o[5] = f2bf(w0 * b0.y + w1 * b1.y + w2 * b2.y + w3 * b3.y);
  o[6] = f2bf(w0 * b0.z + w1 * b1.z + w2 * b2.z + w3 * b3.z);
  o[7] = f2bf(w0 * b0.w + w1 * b1.w + w2 * b2.w + w3 * b3.w);
  *(u16x8*)(retr + (size_t)b * D_ + 8 * l) = o;
}

extern "C" void kernel_launch(void* const* d_in, const int* in_sizes, int n_in,
                              void* d_out, int out_size, void* d_ws, size_t ws_size,
                              hipStream_t stream) {
  (void)in_sizes; (void)n_in; (void)out_size; (void)ws_size;
  const float* query = (const float*)d_in[0];
  const float* keys  = (const float*)d_in[1];
  const float* vals  = (const float*)d_in[2];
  const float* Wq    = (const float*)d_in[3];
  const float* Wv    = (const float*)d_in[4];
  const float* Wg    = (const float*)d_in[5];
  const float* bg    = (const float*)d_in[6];
  float* out = (float*)d_out;

  char* ws = (char*)d_ws;
  const size_t M = 1u << 20;
  unsigned short* sim_bf  = (unsigned short*)(ws);          // [0,32M)
  float*          projF   = (float*)(ws);                   // overlay after topk
  unsigned short* qn_bf   = (unsigned short*)(ws + 32*M);   // [32M,48M)
  unsigned short* retr_bf = (unsigned short*)(ws + 32*M);   // overlay after sim
  unsigned short* proj_bf = (unsigned short*)(ws + 48*M);   // [48M,64M)
  float*          keysN   = (float*)(ws + 64*M);            // 2 MB
  unsigned short* kn_bf   = (unsigned short*)(ws + 66*M);   // 1 MB
  float*          WqT     = (float*)(ws + 67*M);            // 1 MB
  float*          Kp      = (float*)(ws + 68*M);            // 2 MB
  unsigned short* Wq_bf   = (unsigned short*)(ws + 70*M);   // 0.5 MB
  unsigned short* Wv_bf   = (unsigned short*)(ws + 70*M + 512*1024u);
  unsigned short* Wg_bf   = (unsigned short*)(ws + 71*M);   // 1 MB
  float*          invq    = (float*)(ws + 72*M);            // 64 KB

  l2norm_keys<<<E_, 64, 0, stream>>>(keys, keysN, kn_bf);
  transpose512<<<dim3(16, 16), 256, 0, stream>>>(Wq, WqT);
  cvt_bf16<<<(D_ * D_ / 8 + 255) / 256, 256, 0, stream>>>(Wq, Wq_bf, D_ * D_ / 8);
  cvt_bf16<<<(D_ * D_ / 8 + 255) / 256, 256, 0, stream>>>(Wv, Wv_bf, D_ * D_ / 8);
  cvt_bf16<<<(D_ * 2 * D_ / 8 + 255) / 256, 256, 0, stream>>>(Wg, Wg_bf, D_ * 2 * D_ / 8);

  // K' = keysN @ Wq (fp32 rescore basis), 128 blocks
  sgemm64<<<dim3(8, 16), 256, 0, stream>>>(keysN, WqT, Kp);

  // fused q GEMM + norm -> qn_bf + invq
  qgemm_norm<<<B_ / 64, 256, 0, stream>>>(query, Wq_bf, qn_bf, invq);

  // coarse sim (bf16 out): [B,E]
  mfma_nt<512, 1024, 0><<<dim3(E_ / 128, B_ / 128), 256, 0, stream>>>(
      qn_bf, nullptr, nullptr, kn_bf, nullptr, nullptr, nullptr, sim_bf);

  topk_rescore_gather<<<B_ / 4, 256, 0, stream>>>(sim_bf, query, invq, Kp, vals, retr_bf);

  // proj = retrieved @ Wv^T
  mfma_nt<512, 512, 1><<<dim3(D_ / 128, B_ / 128), 256, 0, stream>>>(
      retr_bf, nullptr, nullptr, Wv_bf, nullptr, nullptr, projF, proj_bf);

  // out = sigmoid([query|proj] @ Wg^T + bg) * proj
  mfma_nt<1024, 512, 2><<<dim3(D_ / 128, B_ / 128), 256, 0, stream>>>(
      nullptr, query, proj_bf, Wg_bf, bg, projF, out, nullptr);
}

// Round 7
// 225.180 us; speedup vs baseline: 4.1609x; 1.0453x over previous
//
#include <hip/hip_runtime.h>
#include <hip/hip_bf16.h>
#include <math.h>

// EpisodicMemory round 7.
// - topk v4: register-only, packed-key bitonic merge (1 butterfly, not 4),
//   batch-of-4 pipelined fp32 rescore via Kp, extras serial. No LDS/barriers.
// - projF dropped: gate multiplies bf2f(proj_bf)  (-64MB HBM)
// - qgemm_norm emits query_bf -> gate stages all-A via global_load_lds
// ws layout (<=98 MB):
//   [0,32M)   sim_bf (sim->topk)
//   [32M,48M) qn_bf (q->sim)      -> retr_bf overlay (topk->Wv)
//   [48M,64M) proj_bf (Wv->gate)
//   [64M,66M) keysN  [66M,67M) kn_bf  [67M,68M) WqT  [68M,70M) Kp
//   [70M,70.5M) Wq_bf [70.5M,71M) Wv_bf [71M,72M) Wg_bf [72M,+64K) invq
//   [74M,90M) query_bf

#define B_ 16384
#define D_ 512
#define E_ 1024

typedef __attribute__((ext_vector_type(8))) short bf16x8;
typedef __attribute__((ext_vector_type(4))) float f32x4;
typedef __attribute__((ext_vector_type(8))) unsigned short u16x8;

__device__ __forceinline__ unsigned short f2bf(float f) {
  unsigned u = __builtin_bit_cast(unsigned, f);
  unsigned r = (u + 0x7fffu + ((u >> 16) & 1u)) >> 16;
  return (unsigned short)r;
}
__device__ __forceinline__ float bf2f(unsigned short u) {
  return __builtin_bit_cast(float, (unsigned)u << 16);
}

#define GLDS16(g, l)                                                          \
  __builtin_amdgcn_global_load_lds(                                           \
      (const __attribute__((address_space(1))) void*)(g),                     \
      (__attribute__((address_space(3))) void*)(l), 16, 0, 0)

// ---------- L2 normalize keys: fp32 out + bf16 out ---------------------------
__global__ __launch_bounds__(64) void l2norm_keys(const float* __restrict__ in,
                                                  float* __restrict__ outF,
                                                  unsigned short* __restrict__ outBF) {
  const int row  = blockIdx.x;
  const int lane = threadIdx.x;
  const float4* p4 = (const float4*)(in + (size_t)row * D_);
  float4 a = p4[lane];
  float4 b = p4[lane + 64];
  float ss = a.x*a.x + a.y*a.y + a.z*a.z + a.w*a.w
           + b.x*b.x + b.y*b.y + b.z*b.z + b.w*b.w;
#pragma unroll
  for (int off = 32; off > 0; off >>= 1) ss += __shfl_xor(ss, off, 64);
  const float inv = 1.0f / fmaxf(sqrtf(ss), 1e-12f);
  a.x *= inv; a.y *= inv; a.z *= inv; a.w *= inv;
  b.x *= inv; b.y *= inv; b.z *= inv; b.w *= inv;
  float4* o4 = (float4*)(outF + (size_t)row * D_);
  o4[lane]      = a;
  o4[lane + 64] = b;
  ushort4 ua, ub;
  ua.x=f2bf(a.x); ua.y=f2bf(a.y); ua.z=f2bf(a.z); ua.w=f2bf(a.w);
  ub.x=f2bf(b.x); ub.y=f2bf(b.y); ub.z=f2bf(b.z); ub.w=f2bf(b.w);
  *(ushort4*)(outBF + (size_t)row * D_ + 4*lane)       = ua;
  *(ushort4*)(outBF + (size_t)row * D_ + 256 + 4*lane) = ub;
}

// ---------- 512x512 fp32 transpose (for WqT) ---------------------------------
__global__ __launch_bounds__(256) void transpose512(const float* __restrict__ in,
                                                    float* __restrict__ out) {
  __shared__ float t[32][33];
  const int tx = threadIdx.x & 31, ty = threadIdx.x >> 5;
  const int bx = blockIdx.x, by = blockIdx.y;
#pragma unroll
  for (int k = 0; k < 4; k++)
    t[ty + 8*k][tx] = in[(size_t)(by*32 + ty + 8*k) * 512 + bx*32 + tx];
  __syncthreads();
#pragma unroll
  for (int k = 0; k < 4; k++)
    out[(size_t)(bx*32 + ty + 8*k) * 512 + by*32 + tx] = t[tx][ty + 8*k];
}

// ---------- fp32 NT SGEMM 64x64 tiles (Kp = keysN @ Wq, via WqT) -------------
__global__ __launch_bounds__(256) void sgemm64(const float* __restrict__ A,
                                               const float* __restrict__ Bm,
                                               float* __restrict__ C) {
  __shared__ float As[16][64];
  __shared__ float Bs[16][64];
  const int tid = threadIdx.x;
  const int bn = blockIdx.x, bm = blockIdx.y;
  const int tm = tid >> 4, tn = tid & 15;
  const int r = tid >> 2, k4 = (tid & 3) * 4;
  const float* Ap = A  + (size_t)(bm*64 + r) * 512 + k4;
  const float* Bp = Bm + (size_t)(bn*64 + r) * 512 + k4;
  float acc[4][4];
#pragma unroll
  for (int i = 0; i < 4; i++)
#pragma unroll
    for (int j = 0; j < 4; j++) acc[i][j] = 0.0f;

  for (int k0 = 0; k0 < 512; k0 += 16) {
    const float4 av = *(const float4*)(Ap + k0);
    const float4 bv = *(const float4*)(Bp + k0);
    As[k4+0][r]=av.x; As[k4+1][r]=av.y; As[k4+2][r]=av.z; As[k4+3][r]=av.w;
    Bs[k4+0][r]=bv.x; Bs[k4+1][r]=bv.y; Bs[k4+2][r]=bv.z; Bs[k4+3][r]=bv.w;
    __syncthreads();
#pragma unroll
    for (int k = 0; k < 16; k++) {
      const float4 a = *(const float4*)&As[k][tm*4];
      const float4 b = *(const float4*)&Bs[k][tn*4];
      const float aa[4] = {a.x,a.y,a.z,a.w}, bb[4] = {b.x,b.y,b.z,b.w};
#pragma unroll
      for (int i = 0; i < 4; i++)
#pragma unroll
        for (int j = 0; j < 4; j++) acc[i][j] = fmaf(aa[i], bb[j], acc[i][j]);
    }
    __syncthreads();
  }
#pragma unroll
  for (int i = 0; i < 4; i++) {
    float4 o = make_float4(acc[i][0], acc[i][1], acc[i][2], acc[i][3]);
    *(float4*)(C + (size_t)(bm*64 + tm*4 + i) * 512 + bn*64 + tn*4) = o;
  }
}

// ---------- fp32 -> bf16 conversion ------------------------------------------
__global__ __launch_bounds__(256) void cvt_bf16(const float* __restrict__ in,
                                                unsigned short* __restrict__ out, int n8) {
  const int i = blockIdx.x * 256 + threadIdx.x;
  if (i >= n8) return;
  const float4 a = ((const float4*)in)[2*i];
  const float4 b = ((const float4*)in)[2*i+1];
  u16x8 o;
  o[0]=f2bf(a.x); o[1]=f2bf(a.y); o[2]=f2bf(a.z); o[3]=f2bf(a.w);
  o[4]=f2bf(b.x); o[5]=f2bf(b.y); o[6]=f2bf(b.z); o[7]=f2bf(b.w);
  *(u16x8*)(out + 8*i) = o;
}

// ---------- fused q GEMM + row L2 norm (+ query_bf emit) ---------------------
__global__ __launch_bounds__(256) void qgemm_norm(
    const float* __restrict__ query,
    const unsigned short* __restrict__ Wqbf,
    unsigned short* __restrict__ qnbf,
    unsigned short* __restrict__ qbf,
    float* __restrict__ invq) {
  __shared__ __align__(16) unsigned short As[2][64 * 32];
  __shared__ __align__(16) unsigned short Bs[2][512 * 32];
  __shared__ float rowss[4][64];
  const int tid = threadIdx.x;
  const int wv = tid >> 6, l = tid & 63;
  const int m0 = blockIdx.x * 64;
  const int lane16 = l & 15, lhi = l >> 4;

  f32x4 acc[4][8];
#pragma unroll
  for (int mi = 0; mi < 4; mi++)
#pragma unroll
    for (int nj = 0; nj < 8; nj++)
#pragma unroll
      for (int r = 0; r < 4; r++) acc[mi][nj][r] = 0.0f;

  auto stage = [&](int buf, int t) {
    const int k0 = t * 32;
    {  // A: inline fp32->bf16 cvt + LDS write + query_bf emit
      const int p = tid;
      const int r = p >> 2, c = p & 3;
      const int q = k0 + 8 * (c ^ ((r >> 1) & 3));
      const float* src = query + (size_t)(m0 + r) * 512 + q;
      const float4 f0 = *(const float4*)src;
      const float4 f1 = *(const float4*)(src + 4);
      u16x8 o;
      o[0]=f2bf(f0.x); o[1]=f2bf(f0.y); o[2]=f2bf(f0.z); o[3]=f2bf(f0.w);
      o[4]=f2bf(f1.x); o[5]=f2bf(f1.y); o[6]=f2bf(f1.z); o[7]=f2bf(f1.w);
      *(u16x8*)&As[buf][p * 8] = o;
      *(u16x8*)(qbf + (size_t)(m0 + r) * 512 + q) = o;
    }
#pragma unroll
    for (int h = 0; h < 8; ++h) {
      const int p = tid + 256 * h;
      const int r = p >> 2, c = p & 3;
      const int q = k0 + 8 * (c ^ ((r >> 1) & 3));
      GLDS16(Wqbf + (size_t)r * 512 + q, &Bs[buf][(4 * h + wv) * 512]);
    }
  };
  auto compute = [&](int buf) {
    const int achunk = lhi ^ ((lane16 >> 1) & 3);
    bf16x8 af[4], bfr[8];
#pragma unroll
    for (int mi = 0; mi < 4; ++mi)
      af[mi] = *(const bf16x8*)&As[buf][(mi * 16 + lane16) * 32 + achunk * 8];
#pragma unroll
    for (int nj = 0; nj < 8; ++nj)
      bfr[nj] = *(const bf16x8*)&Bs[buf][(wv * 128 + nj * 16 + lane16) * 32 + achunk * 8];
#pragma unroll
    for (int mi = 0; mi < 4; ++mi)
#pragma unroll
      for (int nj = 0; nj < 8; ++nj)
        acc[mi][nj] = __builtin_amdgcn_mfma_f32_16x16x32_bf16(af[mi], bfr[nj], acc[mi][nj], 0, 0, 0);
  };

  stage(0, 0);
  __syncthreads();
  for (int t = 0; t < 15; ++t) {
    stage((t + 1) & 1, t + 1);
    compute(t & 1);
    __syncthreads();
  }
  compute(1);

  float ss[4][4];
#pragma unroll
  for (int mi = 0; mi < 4; mi++)
#pragma unroll
    for (int r = 0; r < 4; r++) ss[mi][r] = 0.0f;
#pragma unroll
  for (int mi = 0; mi < 4; mi++)
#pragma unroll
    for (int nj = 0; nj < 8; nj++)
#pragma unroll
      for (int r = 0; r < 4; r++) {
        const float x = acc[mi][nj][r];
        ss[mi][r] = fmaf(x, x, ss[mi][r]);
      }
#pragma unroll
  for (int off = 1; off < 16; off <<= 1)
#pragma unroll
    for (int mi = 0; mi < 4; mi++)
#pragma unroll
      for (int r = 0; r < 4; r++) ss[mi][r] += __shfl_xor(ss[mi][r], off, 64);
  if (lane16 == 0) {
#pragma unroll
    for (int mi = 0; mi < 4; mi++)
#pragma unroll
      for (int r = 0; r < 4; r++) rowss[wv][mi * 16 + lhi * 4 + r] = ss[mi][r];
  }
  __syncthreads();

#pragma unroll
  for (int mi = 0; mi < 4; mi++) {
#pragma unroll
    for (int r = 0; r < 4; r++) {
      const int row = mi * 16 + lhi * 4 + r;
      const float tot = rowss[0][row] + rowss[1][row] + rowss[2][row] + rowss[3][row];
      const float inv = 1.0f / fmaxf(sqrtf(tot), 1e-12f);
      if (wv == 0 && lane16 == 0) invq[m0 + row] = inv;
#pragma unroll
      for (int nj = 0; nj < 8; nj++)
        qnbf[(size_t)(m0 + row) * 512 + wv * 128 + nj * 16 + lane16] =
            f2bf(acc[mi][nj][r] * inv);
    }
  }
}

// ---------- bf16 MFMA NT GEMM, 128x128 tile, BK=32, double-buffered ----------
// MODE 0 (sim/wv): A=A0bf;           out: bf16 outbf
// MODE 2 (gate):   A=[A0bf | A1];    out: sigmoid(acc+bg)*bf2f(projbf) -> outf
template<int KTOT, int NOUT, int MODE>
__global__ __launch_bounds__(256) void mfma_nt(
    const unsigned short* __restrict__ A0bf,
    const unsigned short* __restrict__ A1,
    const unsigned short* __restrict__ Bw,
    const float* __restrict__ bg,
    const unsigned short* __restrict__ projbf,
    float* __restrict__ outf,
    unsigned short* __restrict__ outbf) {
  __shared__ __align__(16) unsigned short As[2][128 * 32];
  __shared__ __align__(16) unsigned short Bs[2][128 * 32];
  const int tid = threadIdx.x;
  const int wv = tid >> 6, l = tid & 63;
  const int bn = blockIdx.x, bm = blockIdx.y;
  const int wr = wv >> 1, wc = wv & 1;
  const int lane16 = l & 15, lhi = l >> 4;

  f32x4 acc[4][4];
#pragma unroll
  for (int mi = 0; mi < 4; mi++)
#pragma unroll
    for (int nj = 0; nj < 4; nj++)
#pragma unroll
      for (int r = 0; r < 4; r++) acc[mi][nj][r] = 0.0f;

  auto stage = [&](int buf, int t) {
    const int k0 = t * 32;
#pragma unroll
    for (int h = 0; h < 2; ++h) {
      const int p = tid + 256 * h;
      const int r = p >> 2, c = p & 3;
      const int q = k0 + 8 * (c ^ ((r >> 1) & 3));
      const unsigned short* asrc;
      if constexpr (MODE == 2) {
        asrc = (q < 512) ? (A0bf + (size_t)(bm * 128 + r) * 512 + q)
                         : (A1   + (size_t)(bm * 128 + r) * 512 + (q - 512));
      } else {
        asrc = A0bf + (size_t)(bm * 128 + r) * 512 + q;
      }
      GLDS16(asrc, &As[buf][(4 * h + wv) * 512]);
      const unsigned short* bsrc = Bw + (size_t)(bn * 128 + r) * KTOT + q;
      GLDS16(bsrc, &Bs[buf][(4 * h + wv) * 512]);
    }
  };

  auto compute = [&](int buf) {
    const int achunk = lhi ^ ((lane16 >> 1) & 3);
    bf16x8 af[4], bfr[4];
#pragma unroll
    for (int mi = 0; mi < 4; ++mi)
      af[mi] = *(const bf16x8*)&As[buf][(wr * 64 + mi * 16 + lane16) * 32 + achunk * 8];
#pragma unroll
    for (int nj = 0; nj < 4; ++nj)
      bfr[nj] = *(const bf16x8*)&Bs[buf][(wc * 64 + nj * 16 + lane16) * 32 + achunk * 8];
#pragma unroll
    for (int mi = 0; mi < 4; ++mi)
#pragma unroll
      for (int nj = 0; nj < 4; ++nj)
        acc[mi][nj] = __builtin_amdgcn_mfma_f32_16x16x32_bf16(af[mi], bfr[nj], acc[mi][nj], 0, 0, 0);
  };

  const int NT = KTOT / 32;
  stage(0, 0);
  __syncthreads();
  for (int t = 0; t < NT - 1; ++t) {
    stage((t + 1) & 1, t + 1);
    compute(t & 1);
    __syncthreads();
  }
  compute((NT - 1) & 1);

  const int rowb = bm * 128 + wr * 64 + (lhi << 2);
  const int colb = bn * 128 + wc * 64 + lane16;
#pragma unroll
  for (int mi = 0; mi < 4; ++mi) {
#pragma unroll
    for (int nj = 0; nj < 4; ++nj) {
      const int col = colb + nj * 16;
#pragma unroll
      for (int r = 0; r < 4; ++r) {
        const int row = rowb + mi * 16 + r;
        const size_t o = (size_t)row * NOUT + col;
        const float v = acc[mi][nj][r];
        if constexpr (MODE == 2) {
          const float x = v + bg[col];
          const float g = 1.0f / (1.0f + __expf(-x));
          outf[o] = g * bf2f(projbf[o]);
        } else {
          outbf[o] = f2bf(v);
        }
      }
    }
  }
}

// ---------- topk v4: packed-key coarse top-4 + margin + fp32 rescore ---------
// One wave per row, register-only, no LDS, no barriers.
// packed = sortable-bf16(val)<<16 | (1023-idx): unsigned max == (val desc, idx asc).
__global__ __launch_bounds__(256) void topk_rescore_gather(
    const unsigned short* __restrict__ simbf,
    const float* __restrict__ query,
    const float* __restrict__ invq,
    const float* __restrict__ Kp,
    const float* __restrict__ vals,
    unsigned short* __restrict__ retr) {
  const int w = threadIdx.x >> 6, l = threadIdx.x & 63;
  const int b = blockIdx.x * 4 + w;

  const u16x8* sp = (const u16x8*)(simbf + (size_t)b * E_ + 16 * l);
  const u16x8 s0 = sp[0], s1 = sp[1];
  const float4* qp = (const float4*)(query + (size_t)b * D_ + 8 * l);
  const float4 q0 = qp[0], q1 = qp[1];

  float v[16];
  unsigned pk[16];
#pragma unroll
  for (int j = 0; j < 8; j++) {
    const unsigned u0 = (unsigned short)s0[j];
    const unsigned u1 = (unsigned short)s1[j];
    v[j]     = bf2f((unsigned short)u0);
    v[8 + j] = bf2f((unsigned short)u1);
    const unsigned k0 = u0 ^ ((u0 & 0x8000u) ? 0xFFFFu : 0x8000u);
    const unsigned k1 = u1 ^ ((u1 & 0x8000u) ? 0xFFFFu : 0x8000u);
    pk[j]     = (k0 << 16) | (1023u - (unsigned)(l * 16 + j));
    pk[8 + j] = (k1 << 16) | (1023u - (unsigned)(l * 16 + 8 + j));
  }

  // per-lane top-4 (sorted desc) via branchless insertion
  unsigned t0 = 0, t1 = 0, t2 = 0, t3 = 0;
#pragma unroll
  for (int j = 0; j < 16; j++) {
    const unsigned x = pk[j];
    const unsigned a = min(t0, x); t0 = max(t0, x);
    const unsigned c = min(t1, a); t1 = max(t1, a);
    const unsigned d = min(t2, c); t2 = max(t2, c);
    t3 = max(t3, d);
  }

  // 6-step butterfly bitonic merge -> global top-4 in all lanes
#pragma unroll
  for (int off = 1; off < 64; off <<= 1) {
    const unsigned b0 = (unsigned)__shfl_xor((int)t0, off, 64);
    const unsigned b1 = (unsigned)__shfl_xor((int)t1, off, 64);
    const unsigned b2 = (unsigned)__shfl_xor((int)t2, off, 64);
    const unsigned b3 = (unsigned)__shfl_xor((int)t3, off, 64);
    const unsigned c0 = max(t0, b3), c1 = max(t1, b2);
    const unsigned c2 = max(t2, b1), c3 = max(t3, b0);
    const unsigned d0 = max(c0, c2), d2 = min(c0, c2);
    const unsigned d1 = max(c1, c3), d3 = min(c1, c3);
    t0 = max(d0, d1); t1 = min(d0, d1);
    t2 = max(d2, d3); t3 = min(d2, d3);
  }

  const int i0 = 1023 - (int)(t0 & 1023u);
  const int i1 = 1023 - (int)(t1 & 1023u);
  const int i2 = 1023 - (int)(t2 & 1023u);
  const int i3 = 1023 - (int)(t3 & 1023u);
  const unsigned k16 = t3 >> 16;
  const unsigned u4 = (k16 & 0x8000u) ? (k16 ^ 0x8000u) : (~k16 & 0xFFFFu);
  const float thr = bf2f((unsigned short)u4) - 0.008f;

  // batch rescore of the 4 coarse winners (independent, pipelined)
  const float4* kp0 = (const float4*)(Kp + (size_t)i0 * D_ + 8 * l);
  const float4* kp1 = (const float4*)(Kp + (size_t)i1 * D_ + 8 * l);
  const float4* kp2 = (const float4*)(Kp + (size_t)i2 * D_ + 8 * l);
  const float4* kp3 = (const float4*)(Kp + (size_t)i3 * D_ + 8 * l);
  const float4 a0 = kp0[0], c0 = kp0[1];
  const float4 a1 = kp1[0], c1 = kp1[1];
  const float4 a2 = kp2[0], c2 = kp2[1];
  const float4 a3 = kp3[0], c3 = kp3[1];
  float p0 = q0.x*a0.x, p1 = q0.x*a1.x, p2 = q0.x*a2.x, p3 = q0.x*a3.x;
  p0=fmaf(q0.y,a0.y,p0); p1=fmaf(q0.y,a1.y,p1); p2=fmaf(q0.y,a2.y,p2); p3=fmaf(q0.y,a3.y,p3);
  p0=fmaf(q0.z,a0.z,p0); p1=fmaf(q0.z,a1.z,p1); p2=fmaf(q0.z,a2.z,p2); p3=fmaf(q0.z,a3.z,p3);
  p0=fmaf(q0.w,a0.w,p0); p1=fmaf(q0.w,a1.w,p1); p2=fmaf(q0.w,a2.w,p2); p3=fmaf(q0.w,a3.w,p3);
  p0=fmaf(q1.x,c0.x,p0); p1=fmaf(q1.x,c1.x,p1); p2=fmaf(q1.x,c2.x,p2); p3=fmaf(q1.x,c3.x,p3);
  p0=fmaf(q1.y,c0.y,p0); p1=fmaf(q1.y,c1.y,p1); p2=fmaf(q1.y,c2.y,p2); p3=fmaf(q1.y,c3.y,p3);
  p0=fmaf(q1.z,c0.z,p0); p1=fmaf(q1.z,c1.z,p1); p2=fmaf(q1.z,c2.z,p2); p3=fmaf(q1.z,c3.z,p3);
  p0=fmaf(q1.w,c0.w,p0); p1=fmaf(q1.w,c1.w,p1); p2=fmaf(q1.w,c2.w,p2); p3=fmaf(q1.w,c3.w,p3);
#pragma unroll
  for (int off = 32; off > 0; off >>= 1) {
    p0 += __shfl_xor(p0, off, 64);
    p1 += __shfl_xor(p1, off, 64);
    p2 += __shfl_xor(p2, off, 64);
    p3 += __shfl_xor(p3, off, 64);
  }

  // exact top-4 sorted regs, comparator (value desc, index asc)
  const float NEG = -3.402823466e38f;
  float rv0 = NEG, rv1 = NEG, rv2 = NEG, rv3 = NEG;
  int   ri0 = 0x7fffffff, ri1 = 0x7fffffff, ri2 = 0x7fffffff, ri3 = 0x7fffffff;
  auto ins = [&](float nv, int ni) {
    if (nv > rv0 || (nv == rv0 && ni < ri0)) {
      rv3 = rv2; ri3 = ri2; rv2 = rv1; ri2 = ri1; rv1 = rv0; ri1 = ri0; rv0 = nv; ri0 = ni;
    } else if (nv > rv1 || (nv == rv1 && ni < ri1)) {
      rv3 = rv2; ri3 = ri2; rv2 = rv1; ri2 = ri1; rv1 = nv; ri1 = ni;
    } else if (nv > rv2 || (nv == rv2 && ni < ri2)) {
      rv3 = rv2; ri3 = ri2; rv2 = nv; ri2 = ni;
    } else if (nv > rv3 || (nv == rv3 && ni < ri3)) {
      rv3 = nv; ri3 = ni;
    }
  };
  ins(p0, i0); ins(p1, i1); ins(p2, i2); ins(p3, i3);

  // extras within margin (coarse-4 excluded), serial rescore (expected ~1/row)
  auto score = [&](int idx) -> float {
    const float4* kp = (const float4*)(Kp + (size_t)idx * D_ + 8 * l);
    const float4 k0 = kp[0], k1 = kp[1];
    float p = q0.x * k0.x;
    p = fmaf(q0.y, k0.y, p); p = fmaf(q0.z, k0.z, p); p = fmaf(q0.w, k0.w, p);
    p = fmaf(q1.x, k1.x, p); p = fmaf(q1.y, k1.y, p);
    p = fmaf(q1.z, k1.z, p); p = fmaf(q1.w, k1.w, p);
#pragma unroll
    for (int off = 32; off > 0; off >>= 1) p += __shfl_xor(p, off, 64);
    return p;
  };
#pragma unroll
  for (int s = 0; s < 16; s++) {
    const int idx = l * 16 + s;
    const bool pred = (v[s] >= thr) && idx != i0 && idx != i1 && idx != i2 && idx != i3;
    unsigned long long m = __ballot(pred);
    while (m) {
      const int ln = __builtin_ctzll(m);
      m &= m - 1;
      const int ci = ln * 16 + s;
      ins(score(ci), ci);
    }
  }

  // softmax (positive scale invq preserves ranking)
  const float iq = invq[b];
  const float f0 = rv0 * iq, f1 = rv1 * iq, f2 = rv2 * iq, f3 = rv3 * iq;
  const float mx = 5.0f * f0;
  const float e0 = expf(5.0f * f0 - mx), e1 = expf(5.0f * f1 - mx);
  const float e2 = expf(5.0f * f2 - mx), e3 = expf(5.0f * f3 - mx);
  const float wi = 1.0f / (e0 + e1 + e2 + e3);
  const float w0 = e0 * wi, w1 = e1 * wi, w2 = e2 * wi, w3 = e3 * wi;

  // gather
  const float4* v0p = (const float4*)(vals + (size_t)ri0 * D_ + 8 * l);
  const float4* v1p = (const float4*)(vals + (size_t)ri1 * D_ + 8 * l);
  const float4* v2p = (const float4*)(vals + (size_t)ri2 * D_ + 8 * l);
  const float4* v3p = (const float4*)(vals + (size_t)ri3 * D_ + 8 * l);
  const float4 g0 = v0p[0], h0 = v0p[1];
  const float4 g1 = v1p[0], h1 = v1p[1];
  const float4 g2 = v2p[0], h2 = v2p[1];
  const float4 g3 = v3p[0], h3 = v3p[1];
  u16x8 o;
  o[0] = f2bf(w0 * g0.x + w1 * g1.x + w2 * g2.x + w3 * g3.x);
  o[1] = f2bf(w0 * g0.y + w1 * g1.y + w2 * g2.y + w3 * g3.y);
  o[2] = f2bf(w0 * g0.z + w1 * g1.z + w2 * g2.z + w3 * g3.z);
  o[3] = f2bf(w0 * g0.w + w1 * g1.w + w2 * g2.w + w3 * g3.w);
  o[4] = f2bf(w0 * h0.x + w1 * h1.x + w2 * h2.x + w3 * h3.x);
  o[5] = f2bf(w0 * h0.y + w1 * h1.y + w2 * h2.y + w3 * h3.y);
  o[6] = f2bf(w0 * h0.z + w1 * h1.z + w2 * h2.z + w3 * h3.z);
  o[7] = f2bf(w0 * h0.w + w1 * h1.w + w2 * h2.w + w3 * h3.w);
  *(u16x8*)(retr + (size_t)b * D_ + 8 * l) = o;
}

extern "C" void kernel_launch(void* const* d_in, const int* in_sizes, int n_in,
                              void* d_out, int out_size, void* d_ws, size_t ws_size,
                              hipStream_t stream) {
  (void)in_sizes; (void)n_in; (void)out_size; (void)ws_size;
  const float* query = (const float*)d_in[0];
  const float* keys  = (const float*)d_in[1];
  const float* vals  = (const float*)d_in[2];
  const float* Wq    = (const float*)d_in[3];
  const float* Wv    = (const float*)d_in[4];
  const float* Wg    = (const float*)d_in[5];
  const float* bg    = (const float*)d_in[6];
  float* out = (float*)d_out;

  char* ws = (char*)d_ws;
  const size_t M = 1u << 20;
  unsigned short* sim_bf   = (unsigned short*)(ws);          // [0,32M)
  unsigned short* qn_bf    = (unsigned short*)(ws + 32*M);   // [32M,48M)
  unsigned short* retr_bf  = (unsigned short*)(ws + 32*M);   // overlay after sim
  unsigned short* proj_bf  = (unsigned short*)(ws + 48*M);   // [48M,64M)
  float*          keysN    = (float*)(ws + 64*M);            // 2 MB
  unsigned short* kn_bf    = (unsigned short*)(ws + 66*M);   // 1 MB
  float*          WqT      = (float*)(ws + 67*M);            // 1 MB
  float*          Kp       = (float*)(ws + 68*M);            // 2 MB
  unsigned short* Wq_bf    = (unsigned short*)(ws + 70*M);   // 0.5 MB
  unsigned short* Wv_bf    = (unsigned short*)(ws + 70*M + 512*1024u);
  unsigned short* Wg_bf    = (unsigned short*)(ws + 71*M);   // 1 MB
  float*          invq     = (float*)(ws + 72*M);            // 64 KB
  unsigned short* query_bf = (unsigned short*)(ws + 74*M);   // [74M,90M)

  l2norm_keys<<<E_, 64, 0, stream>>>(keys, keysN, kn_bf);
  transpose512<<<dim3(16, 16), 256, 0, stream>>>(Wq, WqT);
  cvt_bf16<<<(D_ * D_ / 8 + 255) / 256, 256, 0, stream>>>(Wq, Wq_bf, D_ * D_ / 8);
  cvt_bf16<<<(D_ * D_ / 8 + 255) / 256, 256, 0, stream>>>(Wv, Wv_bf, D_ * D_ / 8);
  cvt_bf16<<<(D_ * 2 * D_ / 8 + 255) / 256, 256, 0, stream>>>(Wg, Wg_bf, D_ * 2 * D_ / 8);

  // K' = keysN @ Wq (fp32 rescore basis)
  sgemm64<<<dim3(8, 16), 256, 0, stream>>>(keysN, WqT, Kp);

  // fused q GEMM + norm -> qn_bf + invq + query_bf
  qgemm_norm<<<B_ / 64, 256, 0, stream>>>(query, Wq_bf, qn_bf, query_bf, invq);

  // coarse sim (bf16 out): [B,E]
  mfma_nt<512, 1024, 0><<<dim3(E_ / 128, B_ / 128), 256, 0, stream>>>(
      qn_bf, nullptr, kn_bf, nullptr, nullptr, nullptr, sim_bf);

  topk_rescore_gather<<<B_ / 4, 256, 0, stream>>>(sim_bf, query, invq, Kp, vals, retr_bf);

  // proj = retrieved @ Wv^T (bf16 out only)
  mfma_nt<512, 512, 0><<<dim3(D_ / 128, B_ / 128), 256, 0, stream>>>(
      retr_bf, nullptr, Wv_bf, nullptr, nullptr, nullptr, proj_bf);

  // out = sigmoid([query|proj] @ Wg^T + bg) * proj
  mfma_nt<1024, 512, 2><<<dim3(D_ / 128, B_ / 128), 256, 0, stream>>>(
      query_bf, proj_bf, Wg_bf, bg, proj_bf, out, nullptr);
}